// Round 6
// baseline (54776.227 us; speedup 1.0000x reference)
//
#include <hip/hip_runtime.h>
#include <cstddef>

#define HID   256
#define CTXD  128
#define QDIM  128
#define VDNUM 33

__device__ __forceinline__ float sigf(float x) { return 1.f / (1.f + expf(-x)); }

struct P {
    const int*   seqs;
    const float* key; const float* val; const float* embed;
    const float* Wih0; const float* Whh0; const float* bih0; const float* bhh0;
    const float* Wih1; const float* Whh1; const float* bih1; const float* bhh1;
    const float* Wih2; const float* Whh2; const float* bih2; const float* bhh2;
    const float* Wq;  const float* bq;
    const float* Ws1; const float* bs1;
    const float* Ws2; const float* bs2;
    const float* h0; const float* c0; const float* con;
    float* W0p; float* W1p; float* W2p; float* bsum;  // per-slice packed LSTM weights
    float* WqT4; float* Ws1p; float* Ws2T;
    float* hx0; float* hx1; float* hx2; float* hidx;  // cross-block h exchange
    float* pm; float* pz; float* cp;
    unsigned* flags;
    float* outS; float* outP;
    int S, T;
};

// ---------------------------------------------------------------------------
// Weight repack. W{0,1,2}p layout: [slice i][k4][256 local rows][4 k-lanes],
// local row r -> global row (r>>6)*256 + i*64 + (r&63)  (gate-major).
// Ws1p: [slice i][k4 of 96][64 j][4]. Runs every call (deterministic).
// ---------------------------------------------------------------------------
__global__ void prep(P p)
{
    const int stride = gridDim.x * blockDim.x;
    const int i0 = blockIdx.x * blockDim.x + threadIdx.x;

    for (int z = i0; z < 4 * 160 * 256 * 4; z += stride) {   // L0: K=640
        int lane = z & 3, r = (z >> 2) & 255;
        int rest = z >> 10, k4 = rest % 160, i = rest / 160;
        int k = k4 * 4 + lane;
        int row = (r >> 6) * 256 + i * 64 + (r & 63);
        p.W0p[z] = (k < 384) ? p.Wih0[(size_t)row * 384 + k]
                             : p.Whh0[(size_t)row * 256 + (k - 384)];
    }
    for (int z = i0; z < 4 * 128 * 256 * 4; z += stride) {   // L1,L2: K=512
        int lane = z & 3, r = (z >> 2) & 255;
        int rest = z >> 10, k4 = rest & 127, i = rest >> 7;
        int k = k4 * 4 + lane;
        int row = (r >> 6) * 256 + i * 64 + (r & 63);
        p.W1p[z] = (k < 256) ? p.Wih1[(size_t)row * 256 + k] : p.Whh1[(size_t)row * 256 + (k - 256)];
        p.W2p[z] = (k < 256) ? p.Wih2[(size_t)row * 256 + k] : p.Whh2[(size_t)row * 256 + (k - 256)];
    }
    for (int z = i0; z < 3072; z += stride) {
        int l = z >> 10, r = z & 1023;
        const float* bi = l == 0 ? p.bih0 : l == 1 ? p.bih1 : p.bih2;
        const float* bh = l == 0 ? p.bhh0 : l == 1 ? p.bhh1 : p.bhh2;
        p.bsum[z] = bi[r] + bh[r];
    }
    for (int z = i0; z < 256 * 128; z += stride) {           // WqT4 [k4][128][4]
        int k = z >> 7, q = z & 127;
        p.WqT4[((size_t)(k >> 2) * 128 + q) * 4 + (k & 3)] = p.Wq[(size_t)q * HID + k];
    }
    for (int z = i0; z < 4 * 96 * 64 * 4; z += stride) {     // Ws1p
        int lane = z & 3, j = (z >> 2) & 63;
        int rest = z >> 8, k4 = rest % 96, i = rest / 96;
        int k = k4 * 4 + lane, jg = i * 64 + j;
        p.Ws1p[z] = p.Ws1[(size_t)jg * 384 + k];
    }
    for (int z = i0; z < 256 * VDNUM; z += stride) {         // Ws2T [k][33]
        int k = z / VDNUM, v = z - k * VDNUM;
        p.Ws2T[(size_t)k * VDNUM + v] = p.Ws2[(size_t)v * HID + k];
    }
    for (int z = i0; z < 64 * 4 * 16; z += stride) p.flags[z] = 0u;
}

// ---------------------------------------------------------------------------
// 4-block cluster sync: each block release-stores its own flag (64B apart),
// threads 0..3 spin one flag each (relaxed), acquire fence, syncthreads.
// Skew between cluster blocks is bounded to <2 phases, which makes all
// single-buffered exchange buffers (hx*, pm, pz, cp, hidx) race-free.
// ---------------------------------------------------------------------------
__device__ __forceinline__ void csync(unsigned* flags, int cbase, int i, unsigned& gen)
{
    __syncthreads();
    ++gen;
    if (threadIdx.x == 0)
        __hip_atomic_store(flags + ((cbase + i) << 4), gen, __ATOMIC_RELEASE, __HIP_MEMORY_SCOPE_AGENT);
    if (threadIdx.x < 4) {
        while (__hip_atomic_load(flags + ((cbase + (int)threadIdx.x) << 4),
                                 __ATOMIC_RELAXED, __HIP_MEMORY_SCOPE_AGENT) < gen)
            __builtin_amdgcn_s_sleep(1);
    }
    __builtin_amdgcn_fence(__ATOMIC_ACQUIRE, "agent");
    __syncthreads();
}

// ---------------------------------------------------------------------------
// Persistent kernel: 256 blocks x 512 threads, 4 blocks per batch element.
// Block handles: 256-of-1024 gate rows per LSTM layer, one T-quarter of
// attention, 64-of-256 MLP rows. Query/logits computed redundantly.
// ---------------------------------------------------------------------------
__global__ __launch_bounds__(512) void speller(P p)
{
    __shared__ float h[3][HID], cst[3][64], ctx[CTXD];
    __shared__ float xh0[640], xh12[512];
    __shared__ float gacc[512], gatev[256];
    __shared__ float qry[QDIM];
    __shared__ float e_q[512];           // my quarter: energy -> score
    __shared__ float red[8][CTXD];
    __shared__ float hid[HID];
    __shared__ float predp[264], predv[VDNUM];
    __shared__ float wred[8];
    __shared__ float bc1;
    __shared__ int   chr;

    const int tid = threadIdx.x;
    // XCD-local cluster swizzle (bijective; perf heuristic only):
    // bid = xcd + 8*i + 32*cg  ->  b = xcd + 8*cg, slice = i.
    const int bid = blockIdx.x;
    const int b   = (bid & 7) + ((bid >> 5) << 3);
    const int i   = (bid >> 3) & 3;
    const int cbase = b << 2;
    const int T = p.T, n = p.seqs[b];
    const int t0 = i << 9;
    unsigned gen = 0;

    if (tid < 256) {
        #pragma unroll
        for (int l = 0; l < 3; ++l) h[l][tid] = p.h0[l * 256 + tid];
    }
    if (tid < 64) {
        #pragma unroll
        for (int l = 0; l < 3; ++l) cst[l][tid] = p.c0[l * 256 + i * 64 + tid];
    }
    if (tid < 128) ctx[tid] = p.con[tid];
    if (tid == 0)  chr = 0;
    __syncthreads();

    for (int s = 0; s < p.S; ++s) {
        // ---- Phase A: LSTM layer 0 (x = [emb|ctx|h0_old], K=640) ----
        if (tid < 256) { xh0[tid] = p.embed[(size_t)chr * 256 + tid]; xh0[384 + tid] = h[0][tid]; }
        else if (tid < 384) xh0[tid] = ctx[tid - 256];
        __syncthreads();
        {
            const int r = tid & 255, kh = tid >> 8;
            const float4* w = (const float4*)p.W0p + ((size_t)(i * 160 + kh * 80)) * 256 + r;
            const float* x = xh0 + kh * 320;
            float a0 = 0, a1 = 0, a2 = 0, a3 = 0;
            for (int k4 = 0; k4 < 80; k4 += 4) {
                float4 w0 = w[(size_t)(k4 + 0) * 256];
                float4 w1 = w[(size_t)(k4 + 1) * 256];
                float4 w2 = w[(size_t)(k4 + 2) * 256];
                float4 w3 = w[(size_t)(k4 + 3) * 256];
                const float* xx = x + k4 * 4;
                a0 += xx[0]  * w0.x + xx[1]  * w0.y + xx[2]  * w0.z + xx[3]  * w0.w;
                a1 += xx[4]  * w1.x + xx[5]  * w1.y + xx[6]  * w1.z + xx[7]  * w1.w;
                a2 += xx[8]  * w2.x + xx[9]  * w2.y + xx[10] * w2.z + xx[11] * w2.w;
                a3 += xx[12] * w3.x + xx[13] * w3.y + xx[14] * w3.z + xx[15] * w3.w;
            }
            gacc[tid] = (a0 + a1) + (a2 + a3);
        }
        __syncthreads();
        if (tid < 256)
            gatev[tid] = gacc[tid] + gacc[256 + tid] + p.bsum[(tid >> 6) * 256 + i * 64 + (tid & 63)];
        __syncthreads();
        if (tid < 64) {
            float gi = gatev[tid], gf = gatev[64 + tid], gg = gatev[128 + tid], go = gatev[192 + tid];
            float cn = sigf(gf) * cst[0][tid] + sigf(gi) * tanhf(gg);
            cst[0][tid] = cn;
            p.hx0[(size_t)b * 256 + i * 64 + tid] = sigf(go) * tanhf(cn);
        }
        csync(p.flags, cbase, i, gen);                      // S1
        if (tid < 256) {
            float v = p.hx0[(size_t)b * 256 + tid];
            h[0][tid] = v; xh12[tid] = v; xh12[256 + tid] = h[1][tid];
        }
        __syncthreads();

        // ---- Phase B: LSTM layer 1 ----
        {
            const int r = tid & 255, kh = tid >> 8;
            const float4* w = (const float4*)p.W1p + ((size_t)(i * 128 + kh * 64)) * 256 + r;
            const float* x = xh12 + kh * 256;
            float a0 = 0, a1 = 0, a2 = 0, a3 = 0;
            for (int k4 = 0; k4 < 64; k4 += 4) {
                float4 w0 = w[(size_t)(k4 + 0) * 256];
                float4 w1 = w[(size_t)(k4 + 1) * 256];
                float4 w2 = w[(size_t)(k4 + 2) * 256];
                float4 w3 = w[(size_t)(k4 + 3) * 256];
                const float* xx = x + k4 * 4;
                a0 += xx[0]  * w0.x + xx[1]  * w0.y + xx[2]  * w0.z + xx[3]  * w0.w;
                a1 += xx[4]  * w1.x + xx[5]  * w1.y + xx[6]  * w1.z + xx[7]  * w1.w;
                a2 += xx[8]  * w2.x + xx[9]  * w2.y + xx[10] * w2.z + xx[11] * w2.w;
                a3 += xx[12] * w3.x + xx[13] * w3.y + xx[14] * w3.z + xx[15] * w3.w;
            }
            gacc[tid] = (a0 + a1) + (a2 + a3);
        }
        __syncthreads();
        if (tid < 256)
            gatev[tid] = gacc[tid] + gacc[256 + tid] + p.bsum[1024 + (tid >> 6) * 256 + i * 64 + (tid & 63)];
        __syncthreads();
        if (tid < 64) {
            float gi = gatev[tid], gf = gatev[64 + tid], gg = gatev[128 + tid], go = gatev[192 + tid];
            float cn = sigf(gf) * cst[1][tid] + sigf(gi) * tanhf(gg);
            cst[1][tid] = cn;
            p.hx1[(size_t)b * 256 + i * 64 + tid] = sigf(go) * tanhf(cn);
        }
        csync(p.flags, cbase, i, gen);                      // S2
        if (tid < 256) {
            float v = p.hx1[(size_t)b * 256 + tid];
            h[1][tid] = v; xh12[tid] = v; xh12[256 + tid] = h[2][tid];
        }
        __syncthreads();

        // ---- Phase C: LSTM layer 2 ----
        {
            const int r = tid & 255, kh = tid >> 8;
            const float4* w = (const float4*)p.W2p + ((size_t)(i * 128 + kh * 64)) * 256 + r;
            const float* x = xh12 + kh * 256;
            float a0 = 0, a1 = 0, a2 = 0, a3 = 0;
            for (int k4 = 0; k4 < 64; k4 += 4) {
                float4 w0 = w[(size_t)(k4 + 0) * 256];
                float4 w1 = w[(size_t)(k4 + 1) * 256];
                float4 w2 = w[(size_t)(k4 + 2) * 256];
                float4 w3 = w[(size_t)(k4 + 3) * 256];
                const float* xx = x + k4 * 4;
                a0 += xx[0]  * w0.x + xx[1]  * w0.y + xx[2]  * w0.z + xx[3]  * w0.w;
                a1 += xx[4]  * w1.x + xx[5]  * w1.y + xx[6]  * w1.z + xx[7]  * w1.w;
                a2 += xx[8]  * w2.x + xx[9]  * w2.y + xx[10] * w2.z + xx[11] * w2.w;
                a3 += xx[12] * w3.x + xx[13] * w3.y + xx[14] * w3.z + xx[15] * w3.w;
            }
            gacc[tid] = (a0 + a1) + (a2 + a3);
        }
        __syncthreads();
        if (tid < 256)
            gatev[tid] = gacc[tid] + gacc[256 + tid] + p.bsum[2048 + (tid >> 6) * 256 + i * 64 + (tid & 63)];
        __syncthreads();
        if (tid < 64) {
            float gi = gatev[tid], gf = gatev[64 + tid], gg = gatev[128 + tid], go = gatev[192 + tid];
            float cn = sigf(gf) * cst[2][tid] + sigf(gi) * tanhf(gg);
            cst[2][tid] = cn;
            p.hx2[(size_t)b * 256 + i * 64 + tid] = sigf(go) * tanhf(cn);
        }
        csync(p.flags, cbase, i, gen);                      // S3
        if (tid < 256) h[2][tid] = p.hx2[(size_t)b * 256 + tid];
        __syncthreads();

        // ---- Query (redundant per block): q = Wq h2 + bq ----
        {
            const int q = tid & 127, ch = tid >> 7;
            const float4* w = (const float4*)p.WqT4 + q;
            float a = 0.f;
            #pragma unroll
            for (int u = 0; u < 16; ++u) {
                int k4 = ch * 16 + u;
                float4 wv = w[(size_t)k4 * 128];
                const float* x = &h[2][k4 * 4];
                a += x[0] * wv.x + x[1] * wv.y + x[2] * wv.z + x[3] * wv.w;
            }
            gacc[ch * 128 + q] = a;
        }
        __syncthreads();
        if (tid < 128)
            qry[tid] = p.bq[tid] + ((gacc[tid] + gacc[128 + tid]) + (gacc[256 + tid] + gacc[384 + tid]));
        __syncthreads();

        // ---- Phase D: energy on my T-quarter + partial (max, expsum) ----
        const int t = t0 + tid;
        if (t0 < n) {
            float e = 0.f, ev = -INFINITY;
            const bool valid = t < n;
            if (valid) {
                const float* kp = p.key + (size_t)b * QDIM * T + t;
                float a0 = 0, a1 = 0;
                #pragma unroll 8
                for (int q = 0; q < QDIM; q += 2) {
                    a0 += qry[q]     * kp[(size_t)q * T];
                    a1 += qry[q + 1] * kp[(size_t)(q + 1) * T];
                }
                e = a0 + a1; ev = e;
            }
            e_q[tid] = e;
            #pragma unroll
            for (int off = 32; off; off >>= 1) ev = fmaxf(ev, __shfl_xor(ev, off));
            if ((tid & 63) == 0) wred[tid >> 6] = ev;
            __syncthreads();
            if (tid == 0) {
                float r = wred[0];
                #pragma unroll
                for (int w = 1; w < 8; ++w) r = fmaxf(r, wred[w]);
                bc1 = r;
            }
            __syncthreads();
            const float mq = bc1;
            float z = valid ? expf(e - mq) : 0.f;
            #pragma unroll
            for (int off = 32; off; off >>= 1) z += __shfl_xor(z, off);
            if ((tid & 63) == 0) wred[tid >> 6] = z;
            __syncthreads();
            if (tid == 0) {
                float r = 0.f;
                #pragma unroll
                for (int w = 0; w < 8; ++w) r += wred[w];
                p.pm[b * 4 + i] = mq; p.pz[b * 4 + i] = r;
            }
        } else if (tid == 0) {
            p.pm[b * 4 + i] = -INFINITY; p.pz[b * 4 + i] = 0.f;
        }
        csync(p.flags, cbase, i, gen);                      // S4

        // ---- Phase E: merge stats, scores for my quarter, ctx partial ----
        {
            float pm0 = p.pm[b * 4 + 0], pm1 = p.pm[b * 4 + 1];
            float pm2 = p.pm[b * 4 + 2], pm3 = p.pm[b * 4 + 3];
            float pz0 = p.pz[b * 4 + 0], pz1 = p.pz[b * 4 + 1];
            float pz2 = p.pz[b * 4 + 2], pz3 = p.pz[b * 4 + 3];
            float m = fmaxf(fmaxf(pm0, pm1), fmaxf(pm2, pm3));
            float Z = pz0 * expf(pm0 - m) + pz1 * expf(pm1 - m)
                    + pz2 * expf(pm2 - m) + pz3 * expf(pm3 - m);
            float sc = 0.f;
            if (t < n) sc = expf(e_q[tid] - m) / Z;
            p.outS[((size_t)b * p.S + s) * T + t] = sc;
            e_q[tid] = sc;
        }
        __syncthreads();
        {
            const int c4 = tid & 31, tg = tid >> 5;
            const float4* v4 = (const float4*)p.val + (size_t)b * T * 32 + c4;
            float ax = 0, ay = 0, az = 0, aw = 0;
            const int tend = min(t0 + 512, n);
            for (int t2 = t0 + tg; t2 < tend; t2 += 16) {
                float  sv = e_q[t2 - t0];
                float4 vv = v4[(size_t)t2 * 32];
                ax += sv * vv.x; ay += sv * vv.y; az += sv * vv.z; aw += sv * vv.w;
            }
            ax += __shfl_xor(ax, 32); ay += __shfl_xor(ay, 32);
            az += __shfl_xor(az, 32); aw += __shfl_xor(aw, 32);
            if ((tid & 63) < 32) {
                const int w = tid >> 6;
                red[w][c4 * 4 + 0] = ax; red[w][c4 * 4 + 1] = ay;
                red[w][c4 * 4 + 2] = az; red[w][c4 * 4 + 3] = aw;
            }
        }
        __syncthreads();
        if (tid < 128) {
            float a = 0.f;
            #pragma unroll
            for (int w = 0; w < 8; ++w) a += red[w][tid];
            p.cp[(size_t)(b * 4 + i) * 128 + tid] = a;
        }
        csync(p.flags, cbase, i, gen);                      // S5

        // ---- Phase F: ctx reduce (redundant), MLP1 on my 64 rows ----
        if (tid < 128) {
            float a = p.cp[(size_t)(b * 4 + 0) * 128 + tid] + p.cp[(size_t)(b * 4 + 1) * 128 + tid]
                    + p.cp[(size_t)(b * 4 + 2) * 128 + tid] + p.cp[(size_t)(b * 4 + 3) * 128 + tid];
            ctx[tid] = a;
            xh0[256 + tid] = a;
        }
        if (tid < 256) xh0[tid] = h[2][tid];
        __syncthreads();
        {
            const int j = tid & 63, ch = tid >> 6;
            const float4* w = (const float4*)p.Ws1p + ((size_t)(i * 96 + ch * 12)) * 64 + j;
            const float* x = xh0 + ch * 48;
            float a0 = 0, a1 = 0, a2 = 0;
            #pragma unroll
            for (int u = 0; u < 12; u += 3) {
                float4 w0 = w[(size_t)(u + 0) * 64];
                float4 w1 = w[(size_t)(u + 1) * 64];
                float4 w2 = w[(size_t)(u + 2) * 64];
                const float* xx = x + u * 4;
                a0 += xx[0] * w0.x + xx[1] * w0.y + xx[2]  * w0.z + xx[3]  * w0.w;
                a1 += xx[4] * w1.x + xx[5] * w1.y + xx[6]  * w1.z + xx[7]  * w1.w;
                a2 += xx[8] * w2.x + xx[9] * w2.y + xx[10] * w2.z + xx[11] * w2.w;
            }
            gacc[ch * 64 + j] = (a0 + a1) + a2;
        }
        __syncthreads();
        if (tid < 64) {
            float a = p.bs1[i * 64 + tid];
            #pragma unroll
            for (int ch = 0; ch < 8; ++ch) a += gacc[ch * 64 + tid];
            p.hidx[(size_t)b * 256 + i * 64 + tid] = fmaxf(a, 0.f);
        }
        csync(p.flags, cbase, i, gen);                      // S6

        // ---- Phase G: predict (redundant), argmax feedback ----
        if (tid < 256) hid[tid] = p.hidx[(size_t)b * 256 + tid];
        __syncthreads();
        if (tid < 264) {
            const int v = tid >> 3, oct = tid & 7;
            const float* w2 = p.Ws2T + (size_t)oct * 32 * VDNUM + v;
            float a = 0.f;
            #pragma unroll 8
            for (int k = 0; k < 32; ++k) a += hid[oct * 32 + k] * w2[(size_t)k * VDNUM];
            predp[tid] = a;
        }
        __syncthreads();
        if (tid < VDNUM) {
            float a = p.bs2[tid];
            #pragma unroll
            for (int o = 0; o < 8; ++o) a += predp[tid * 8 + o];
            predv[tid] = a;
            if (i == 0) p.outP[((size_t)b * p.S + s) * VDNUM + tid] = a;
        }
        __syncthreads();
        if (tid == 0) {   // first-occurrence argmax (strict >)
            int best = 0; float bv = predv[0];
            for (int v = 1; v < VDNUM; ++v) if (predv[v] > bv) { bv = predv[v]; best = v; }
            chr = best;
        }
        __syncthreads();
    }
}

extern "C" void kernel_launch(void* const* d_in, const int* in_sizes, int n_in,
                              void* d_out, int out_size, void* d_ws, size_t ws_size,
                              hipStream_t stream)
{
    P p;
    p.seqs  = (const int*)  d_in[0];
    p.key   = (const float*)d_in[1];
    p.val   = (const float*)d_in[2];
    p.embed = (const float*)d_in[4];
    p.Wih0  = (const float*)d_in[5];  p.Whh0 = (const float*)d_in[6];
    p.bih0  = (const float*)d_in[7];  p.bhh0 = (const float*)d_in[8];
    p.Wih1  = (const float*)d_in[9];  p.Whh1 = (const float*)d_in[10];
    p.bih1  = (const float*)d_in[11]; p.bhh1 = (const float*)d_in[12];
    p.Wih2  = (const float*)d_in[13]; p.Whh2 = (const float*)d_in[14];
    p.bih2  = (const float*)d_in[15]; p.bhh2 = (const float*)d_in[16];
    p.Wq    = (const float*)d_in[17]; p.bq   = (const float*)d_in[18];
    p.Ws1   = (const float*)d_in[19]; p.bs1  = (const float*)d_in[20];
    p.Ws2   = (const float*)d_in[21]; p.bs2  = (const float*)d_in[22];
    p.h0    = (const float*)d_in[23];
    p.c0    = (const float*)d_in[24];
    p.con   = (const float*)d_in[25];

    const int B = in_sizes[0];                  // 64
    p.T = in_sizes[1] / (B * QDIM);             // 2048
    p.S = in_sizes[3] / B;                      // 220

    float* ws = (float*)d_ws;
    p.W0p   = ws;                               // 655360
    p.W1p   = ws + 655360;                      // 524288
    p.W2p   = ws + 1179648;                     // 524288
    p.bsum  = ws + 1703936;                     // 3072
    p.WqT4  = ws + 1707008;                     // 32768
    p.Ws1p  = ws + 1739776;                     // 98304
    p.Ws2T  = ws + 1838080;                     // 8448
    p.hx0   = ws + 1846528;                     // 16384
    p.hx1   = ws + 1862912;                     // 16384
    p.hx2   = ws + 1879296;                     // 16384
    p.hidx  = ws + 1895680;                     // 16384
    p.pm    = ws + 1912064;                     // 256
    p.pz    = ws + 1912320;                     // 256
    p.cp    = ws + 1912576;                     // 32768
    p.flags = (unsigned*)(ws + 1945344);        // 4096

    p.outS = (float*)d_out;
    p.outP = p.outS + (size_t)B * p.S * p.T;

    prep<<<1024, 256, 0, stream>>>(p);
    speller<<<256, 512, 0, stream>>>(p);
}

// Round 8
// 21954.422 us; speedup vs baseline: 2.4950x; 2.4950x over previous
//
#include <hip/hip_runtime.h>
#include <cstddef>

#define HID   256
#define CTXD  128
#define QDIM  128
#define VDNUM 33

typedef float  float4e __attribute__((ext_vector_type(4)));
typedef unsigned int uint4e __attribute__((ext_vector_type(4)));

__device__ __forceinline__ float sigf(float x) { return 1.f / (1.f + expf(-x)); }

union H8 { uint4e u; _Float16 h[8]; };

struct P {
    const int*   seqs;
    const float* key; const float* val; const float* embed;
    const float* Wih0; const float* Whh0; const float* bih0; const float* bhh0;
    const float* Wih1; const float* Whh1; const float* bih1; const float* bhh1;
    const float* Wih2; const float* Whh2; const float* bih2; const float* bhh2;
    const float* Wq;  const float* bq;
    const float* Ws1; const float* bs1;
    const float* Ws2; const float* bs2;
    const float* h0; const float* c0; const float* con;
    unsigned short* WH0; unsigned short* WH1; unsigned short* WH2;  // fp16 LSTM weights
    unsigned short* Ws1h;                                           // fp16 MLP1 weights
    float* bsum; float* WqT4; float* Ws2T;
    float* outS; float* outP;
    int S, T;
};

// ---------------------------------------------------------------------------
// Weight repack to fp16, chunk-of-8 layout: WH[(c*1024 + r)*8 + j] holds
// w[row r][k = c*8+j]. A thread owning row r loads one uint4 (8 halves) per
// chunk; lanes r coalesced (1KB/wave-instr). 2 pad chunks at the end absorb
// unconditional prefetch reads. fp16 keeps the per-XCD weight working set
// (3.6 MB) inside the 4 MB L2. Runs every call (deterministic).
// ---------------------------------------------------------------------------
__global__ void prep(P p)
{
    const int stride = gridDim.x * blockDim.x;
    const int i0 = blockIdx.x * blockDim.x + threadIdx.x;

    _Float16* w0 = (_Float16*)p.WH0;
    for (int z = i0; z < 80 * 8192; z += stride) {           // L0: K=640
        int c = z >> 13, rem = z & 8191, r = rem >> 3, j = rem & 7;
        int k = c * 8 + j;
        float v = (k < 384) ? p.Wih0[(size_t)r * 384 + k]
                            : p.Whh0[(size_t)r * 256 + (k - 384)];
        w0[z] = (_Float16)v;
    }
    _Float16* w1 = (_Float16*)p.WH1;
    _Float16* w2 = (_Float16*)p.WH2;
    for (int z = i0; z < 64 * 8192; z += stride) {           // L1,L2: K=512
        int c = z >> 13, rem = z & 8191, r = rem >> 3, j = rem & 7;
        int k = c * 8 + j;
        w1[z] = (_Float16)((k < 256) ? p.Wih1[(size_t)r * 256 + k]
                                     : p.Whh1[(size_t)r * 256 + (k - 256)]);
        w2[z] = (_Float16)((k < 256) ? p.Wih2[(size_t)r * 256 + k]
                                     : p.Whh2[(size_t)r * 256 + (k - 256)]);
    }
    _Float16* ws1 = (_Float16*)p.Ws1h;
    for (int z = i0; z < 48 * 2048; z += stride) {           // Ws1: [256 j][384 k]
        int c = z >> 11, rem = z & 2047, j = rem >> 3, lane = rem & 7;
        int k = c * 8 + lane;
        ws1[z] = (_Float16)p.Ws1[(size_t)j * 384 + k];
    }
    for (int z = i0; z < 3072; z += stride) {                // bih+bhh fused
        int l = z >> 10, r = z & 1023;
        const float* bi = l == 0 ? p.bih0 : l == 1 ? p.bih1 : p.bih2;
        const float* bh = l == 0 ? p.bhh0 : l == 1 ? p.bhh1 : p.bhh2;
        p.bsum[z] = bi[r] + bh[r];
    }
    for (int z = i0; z < 256 * 128; z += stride) {           // WqT4 [k4][128][4] fp32
        int k = z >> 7, q = z & 127;
        p.WqT4[((size_t)(k >> 2) * 128 + q) * 4 + (k & 3)] = p.Wq[(size_t)q * HID + k];
    }
    for (int z = i0; z < 256 * VDNUM; z += stride) {         // Ws2T [k][33] fp32
        int k = z / VDNUM, v = z - k * VDNUM;
        p.Ws2T[(size_t)k * VDNUM + v] = p.Ws2[(size_t)v * HID + k];
    }
}

// ---------------------------------------------------------------------------
// LSTM matvec helper: thread owns gate-row `tid`; loops over K in chunks of
// 16 halves (2 uint4e loads) with explicit next-iteration register prefetch.
// x comes from LDS (wave-uniform broadcast reads).
// ---------------------------------------------------------------------------
template<int NCH>  // number of 8-wide chunks (80 for L0, 64 for L1/L2)
__device__ __forceinline__ float matvec_h8(const unsigned short* W, int tid, const float* x)
{
    const uint4e* w = (const uint4e*)W + tid;    // chunk stride = 1024 uint4e
    H8 c0, c1;
    c0.u = w[0]; c1.u = w[1024];
    float a0 = 0.f, a1 = 0.f;
    #pragma unroll 2
    for (int c = 0; c < NCH; c += 2) {
        H8 n0, n1;
        n0.u = w[(size_t)(c + 2) * 1024];      // pad chunks absorb overrun
        n1.u = w[(size_t)(c + 3) * 1024];
        const float* xx = x + c * 8;
        a0 += (float)c0.h[0] * xx[0]  + (float)c0.h[1] * xx[1]
            + (float)c0.h[2] * xx[2]  + (float)c0.h[3] * xx[3];
        a1 += (float)c0.h[4] * xx[4]  + (float)c0.h[5] * xx[5]
            + (float)c0.h[6] * xx[6]  + (float)c0.h[7] * xx[7];
        a0 += (float)c1.h[0] * xx[8]  + (float)c1.h[1] * xx[9]
            + (float)c1.h[2] * xx[10] + (float)c1.h[3] * xx[11];
        a1 += (float)c1.h[4] * xx[12] + (float)c1.h[5] * xx[13]
            + (float)c1.h[6] * xx[14] + (float)c1.h[7] * xx[15];
        c0 = n0; c1 = n1;
    }
    return a0 + a1;
}

// ---------------------------------------------------------------------------
// Persistent per-batch-element kernel: 64 blocks x 1024 threads, one block
// per b, entire 220-step recurrence in-block, ZERO device-scope sync (round-5
// lesson: agent fences invalidate L2 and destroy weight residency).
// Weights fp16 + prefetch; key/val/outputs non-temporal to protect L2.
// ---------------------------------------------------------------------------
__global__ __launch_bounds__(1024, 4) void speller(P p)
{
    __shared__ float h[3][HID], c[3][HID], ctx[CTXD];
    __shared__ float xh0[640];            // [emb 256 | ctx 128 | h0 256]; reused as MLP feat
    __shared__ float xh12[512];           // LSTM L1/L2 input [h_prev_layer | h_own_old]
    __shared__ float gacc[1024];
    __shared__ float qry[QDIM];
    __shared__ float s_sc[2048];          // energies -> p -> scores
    __shared__ float red[16][CTXD];
    __shared__ float hid[HID];
    __shared__ float predp[VDNUM * 8];
    __shared__ float predv[VDNUM];
    __shared__ float wred[16];
    __shared__ float bcast;
    __shared__ int   chr;

    const int b   = blockIdx.x;
    const int tid = threadIdx.x;
    const int T   = p.T;
    const int n   = p.seqs[b];

    if (tid < HID) {
        #pragma unroll
        for (int l = 0; l < 3; ++l) { h[l][tid] = p.h0[l * HID + tid]; c[l][tid] = p.c0[l * HID + tid]; }
    }
    if (tid < CTXD) ctx[tid] = p.con[tid];
    if (tid == 0)   chr = 0;
    __syncthreads();

    for (int s = 0; s < p.S; ++s) {
        // ---- build L0 input ----
        if (tid < 256)      xh0[tid] = p.embed[(size_t)chr * HID + tid];
        else if (tid < 384) xh0[tid] = ctx[tid - 256];
        else if (tid < 640) xh0[tid] = h[0][tid - 384];
        __syncthreads();

        // ---- L0 (K=640, 80 chunks) ----
        gacc[tid] = p.bsum[tid] + matvec_h8<80>(p.WH0, tid, xh0);
        __syncthreads();
        if (tid < HID) {   // gate order i,f,g,o
            float gi = gacc[tid], gf = gacc[256 + tid], gg = gacc[512 + tid], go = gacc[768 + tid];
            float cn = sigf(gf) * c[0][tid] + sigf(gi) * tanhf(gg);
            c[0][tid] = cn;
            float hn = sigf(go) * tanhf(cn);
            h[0][tid] = hn;
            xh12[tid] = hn; xh12[256 + tid] = h[1][tid];
        }
        __syncthreads();

        // ---- L1 (K=512, 64 chunks) ----
        gacc[tid] = p.bsum[1024 + tid] + matvec_h8<64>(p.WH1, tid, xh12);
        __syncthreads();
        if (tid < HID) {
            float gi = gacc[tid], gf = gacc[256 + tid], gg = gacc[512 + tid], go = gacc[768 + tid];
            float cn = sigf(gf) * c[1][tid] + sigf(gi) * tanhf(gg);
            c[1][tid] = cn;
            float hn = sigf(go) * tanhf(cn);
            h[1][tid] = hn;
            xh12[tid] = hn; xh12[256 + tid] = h[2][tid];
        }
        __syncthreads();

        // ---- L2 (K=512, 64 chunks) ----
        gacc[tid] = p.bsum[2048 + tid] + matvec_h8<64>(p.WH2, tid, xh12);
        __syncthreads();
        if (tid < HID) {
            float gi = gacc[tid], gf = gacc[256 + tid], gg = gacc[512 + tid], go = gacc[768 + tid];
            float cn = sigf(gf) * c[2][tid] + sigf(gi) * tanhf(gg);
            c[2][tid] = cn;
            h[2][tid] = sigf(go) * tanhf(cn);
        }
        __syncthreads();

        // ---- query = h2 @ Wq^T + bq (fp32, 8 k-chunks x 128 q) ----
        {
            const int q = tid & 127, ch = tid >> 7;
            const float4e* w = (const float4e*)p.WqT4 + q;
            float a = 0;
            #pragma unroll
            for (int i = 0; i < 8; ++i) {
                int k4 = ch * 8 + i;
                float4e wv = w[(size_t)k4 * 128];
                const float* x = &h[2][k4 * 4];
                a += x[0] * wv.x + x[1] * wv.y + x[2] * wv.z + x[3] * wv.w;
            }
            gacc[ch * 128 + q] = a;
        }
        __syncthreads();
        if (tid < QDIM) {
            float a = p.bq[tid];
            #pragma unroll
            for (int i = 0; i < 8; ++i) a += gacc[i * 128 + tid];
            qry[tid] = a;
        }
        __syncthreads();

        // ---- energy over t<n + max (non-temporal key reads) ----
        float m = -INFINITY;
        for (int t = tid; t < T; t += 1024) {
            float a = 0.f;
            if (t < n) {
                const float* kp = p.key + (size_t)b * QDIM * T + t;
                float a0 = 0, a1 = 0;
                #pragma unroll 4
                for (int q = 0; q < QDIM; q += 2) {
                    a0 += qry[q]     * __builtin_nontemporal_load(kp + (size_t)q * T);
                    a1 += qry[q + 1] * __builtin_nontemporal_load(kp + (size_t)(q + 1) * T);
                }
                a = a0 + a1;
                m = fmaxf(m, a);
            }
            s_sc[t] = a;
        }
        #pragma unroll
        for (int off = 32; off; off >>= 1) m = fmaxf(m, __shfl_xor(m, off));
        if ((tid & 63) == 0) wred[tid >> 6] = m;
        __syncthreads();
        if (tid == 0) {
            float r = wred[0];
            #pragma unroll
            for (int i = 1; i < 16; ++i) r = fmaxf(r, wred[i]);
            bcast = r;
        }
        __syncthreads();
        m = bcast;

        // ---- exp + sum ----
        float z = 0.f;
        for (int t = tid; t < T; t += 1024) {
            float pv = 0.f;
            if (t < n) { pv = expf(s_sc[t] - m); z += pv; }
            s_sc[t] = pv;
        }
        #pragma unroll
        for (int off = 32; off; off >>= 1) z += __shfl_xor(z, off);
        if ((tid & 63) == 0) wred[tid >> 6] = z;
        __syncthreads();
        if (tid == 0) {
            float r = 0.f;
            #pragma unroll
            for (int i = 0; i < 16; ++i) r += wred[i];
            bcast = r;
        }
        __syncthreads();
        const float Z = bcast;

        // ---- scores out (zeros beyond n; masked+renorm algebra) ----
        float* so = p.outS + ((size_t)b * p.S + s) * T;
        for (int t = tid; t < T; t += 1024) {
            float sc = s_sc[t] / Z;
            s_sc[t] = sc;
            __builtin_nontemporal_store(sc, so + t);
        }
        __syncthreads();

        // ---- ctx = sum_{t<n} score[t] * val[b][t][:] (non-temporal val) ----
        {
            const int tg = tid >> 5, cq = tid & 31;
            const float4e* v4 = (const float4e*)p.val + (size_t)b * T * 32 + cq;
            float ax = 0, ay = 0, az = 0, aw = 0;
            for (int t = tg; t < n; t += 32) {
                float  sv = s_sc[t];
                float4e vv = __builtin_nontemporal_load(v4 + (size_t)t * 32);
                ax += sv * vv.x; ay += sv * vv.y; az += sv * vv.z; aw += sv * vv.w;
            }
            ax += __shfl_xor(ax, 32); ay += __shfl_xor(ay, 32);
            az += __shfl_xor(az, 32); aw += __shfl_xor(aw, 32);
            if ((tid & 63) < 32) {
                const int w = tid >> 6;
                red[w][cq * 4 + 0] = ax; red[w][cq * 4 + 1] = ay;
                red[w][cq * 4 + 2] = az; red[w][cq * 4 + 3] = aw;
            }
        }
        __syncthreads();
        if (tid < CTXD) {
            float a = 0.f;
            #pragma unroll
            for (int w = 0; w < 16; ++w) a += red[w][tid];
            ctx[tid] = a;
            xh0[256 + tid] = a;          // feat = [h2 | ctx_new]
        }
        if (tid < HID) xh0[tid] = h[2][tid];
        __syncthreads();

        // ---- MLP1: hid = relu(feat @ Ws1^T + bs1), fp16 weights + prefetch ----
        {
            const int j = tid & 255, ch = tid >> 8;
            const uint4e* w = (const uint4e*)p.Ws1h + (size_t)(ch * 12) * 256 + j;
            H8 cc; cc.u = w[0];
            float a = 0.f;
            #pragma unroll 2
            for (int u = 0; u < 12; ++u) {
                H8 nx; nx.u = w[(size_t)(u + 1) * 256];   // pad chunk absorbs overrun
                const float* x = xh0 + (ch * 12 + u) * 8;
                a += (float)cc.h[0] * x[0] + (float)cc.h[1] * x[1]
                   + (float)cc.h[2] * x[2] + (float)cc.h[3] * x[3]
                   + (float)cc.h[4] * x[4] + (float)cc.h[5] * x[5]
                   + (float)cc.h[6] * x[6] + (float)cc.h[7] * x[7];
                cc = nx;
            }
            gacc[ch * 256 + j] = a;
        }
        __syncthreads();
        if (tid < HID)
            hid[tid] = fmaxf(p.bs1[tid] + ((gacc[tid] + gacc[256 + tid]) + (gacc[512 + tid] + gacc[768 + tid])), 0.f);
        __syncthreads();

        // ---- predict = hid @ Ws2^T + bs2 (fp32); argmax feedback ----
        if (tid < VDNUM * 8) {
            const int v = tid >> 3, oct = tid & 7;
            const float* w2 = p.Ws2T + (size_t)oct * 32 * VDNUM + v;
            float a = 0.f;
            #pragma unroll 8
            for (int k = 0; k < 32; ++k) a += hid[oct * 32 + k] * w2[(size_t)k * VDNUM];
            predp[v * 8 + oct] = a;
        }
        __syncthreads();
        if (tid < VDNUM) {
            float a = p.bs2[tid];
            #pragma unroll
            for (int o = 0; o < 8; ++o) a += predp[tid * 8 + o];
            __builtin_nontemporal_store(a, p.outP + ((size_t)b * p.S + s) * VDNUM + tid);
            predv[tid] = a;
        }
        __syncthreads();
        if (tid == 0) {   // first-occurrence argmax (strict >)
            int best = 0; float bv = predv[0];
            for (int v = 1; v < VDNUM; ++v) if (predv[v] > bv) { bv = predv[v]; best = v; }
            chr = best;
        }
        __syncthreads();
    }
}

extern "C" void kernel_launch(void* const* d_in, const int* in_sizes, int n_in,
                              void* d_out, int out_size, void* d_ws, size_t ws_size,
                              hipStream_t stream)
{
    P p;
    p.seqs  = (const int*)  d_in[0];
    p.key   = (const float*)d_in[1];
    p.val   = (const float*)d_in[2];
    p.embed = (const float*)d_in[4];
    p.Wih0  = (const float*)d_in[5];  p.Whh0 = (const float*)d_in[6];
    p.bih0  = (const float*)d_in[7];  p.bhh0 = (const float*)d_in[8];
    p.Wih1  = (const float*)d_in[9];  p.Whh1 = (const float*)d_in[10];
    p.bih1  = (const float*)d_in[11]; p.bhh1 = (const float*)d_in[12];
    p.Wih2  = (const float*)d_in[13]; p.Whh2 = (const float*)d_in[14];
    p.bih2  = (const float*)d_in[15]; p.bhh2 = (const float*)d_in[16];
    p.Wq    = (const float*)d_in[17]; p.bq   = (const float*)d_in[18];
    p.Ws1   = (const float*)d_in[19]; p.bs1  = (const float*)d_in[20];
    p.Ws2   = (const float*)d_in[21]; p.bs2  = (const float*)d_in[22];
    p.h0    = (const float*)d_in[23];
    p.c0    = (const float*)d_in[24];
    p.con   = (const float*)d_in[25];

    const int B = in_sizes[0];                  // 64
    p.T = in_sizes[1] / (B * QDIM);             // 2048
    p.S = in_sizes[3] / B;                      // 220

    // workspace layout (bytes; all 16B-aligned). fp16 weights with pad chunks.
    char* ws = (char*)d_ws;
    p.WH0  = (unsigned short*)(ws + 0);          // 82 chunks * 8192 halves = 1,343,488 B
    p.WH1  = (unsigned short*)(ws + 1343488);    // 66 * 8192 halves       = 1,081,344 B
    p.WH2  = (unsigned short*)(ws + 2424832);    // 1,081,344 B
    p.Ws1h = (unsigned short*)(ws + 3506176);    // 49 * 2048 halves       =   200,704 B
    p.bsum = (float*)(ws + 3706880);             // 3072 f                 =    12,288 B
    p.WqT4 = (float*)(ws + 3719168);             // 32768 f                =   131,072 B
    p.Ws2T = (float*)(ws + 3850240);             // 8448 f                 =    33,792 B

    p.outS = (float*)d_out;
    p.outP = p.outS + (size_t)B * p.S * p.T;

    prep<<<1024, 256, 0, stream>>>(p);
    speller<<<B, 1024, 0, stream>>>(p);
}

// Round 9
// 20147.430 us; speedup vs baseline: 2.7188x; 1.0897x over previous
//
#include <hip/hip_runtime.h>
#include <cstddef>

#define HID   256
#define CTXD  128
#define QDIM  128
#define VDNUM 33

typedef float  float4e __attribute__((ext_vector_type(4)));
typedef unsigned int uint4e __attribute__((ext_vector_type(4)));

__device__ __forceinline__ float sigf(float x) { return 1.f / (1.f + expf(-x)); }

union H8 { uint4e u; _Float16 h[8]; };

struct P {
    const int*   seqs;
    const float* key; const float* val; const float* embed;
    const float* Wih0; const float* Whh0; const float* bih0; const float* bhh0;
    const float* Wih1; const float* Whh1; const float* bih1; const float* bhh1;
    const float* Wih2; const float* Whh2; const float* bih2; const float* bhh2;
    const float* Wq;  const float* bq;
    const float* Ws1; const float* bs1;
    const float* Ws2; const float* bs2;
    const float* h0; const float* c0; const float* con;
    unsigned short* WH0; unsigned short* WH1; unsigned short* WH2;  // fp16 LSTM weights
    unsigned short* Ws1h;                                           // fp16 MLP1 weights
    float* bsum; float* WqT4; float* Ws2T; float* Ep;
    float* outS; float* outP;
    int S, T;
};

// ---------------------------------------------------------------------------
// Weight repack to fp16, chunk-of-8 layout: WH[(c*1024 + r)*8 + j] holds
// w[row r][k = c*8+j]. A thread owning row r loads one uint4e (8 halves) per
// chunk, lanes coalesced. 8 pad chunks at the end absorb the depth-8
// prefetch overrun. L0's embed columns are folded into Ep[char][row]
// (exact fp32), so L0 streams only the [ctx(128)|h(256)] columns (K=384).
// Runs every call (deterministic).
// ---------------------------------------------------------------------------
__global__ void prep(P p)
{
    const int stride = gridDim.x * blockDim.x;
    const int i0 = blockIdx.x * blockDim.x + threadIdx.x;

    // Ep[c][r] = sum_k embed[c][k] * Wih0[r][k], k<256 (exact fp32)
    for (int z = i0; z < VDNUM * 1024; z += stride) {
        int c = z >> 10, r = z & 1023;
        const float* w = p.Wih0 + (size_t)r * 384;
        const float* e = p.embed + c * HID;
        float a = 0.f;
        #pragma unroll 8
        for (int k = 0; k < HID; ++k) a += e[k] * w[k];
        p.Ep[z] = a;
    }

    _Float16* w0 = (_Float16*)p.WH0;
    for (int z = i0; z < 48 * 8192; z += stride) {           // L0: K=384 = [ctx|h]
        int c = z >> 13, rem = z & 8191, r = rem >> 3, j = rem & 7;
        int k = c * 8 + j;
        float v = (k < 128) ? p.Wih0[(size_t)r * 384 + 256 + k]   // ctx cols
                            : p.Whh0[(size_t)r * 256 + (k - 128)];
        w0[z] = (_Float16)v;
    }
    _Float16* w1 = (_Float16*)p.WH1;
    _Float16* w2 = (_Float16*)p.WH2;
    for (int z = i0; z < 64 * 8192; z += stride) {           // L1,L2: K=512
        int c = z >> 13, rem = z & 8191, r = rem >> 3, j = rem & 7;
        int k = c * 8 + j;
        w1[z] = (_Float16)((k < 256) ? p.Wih1[(size_t)r * 256 + k]
                                     : p.Whh1[(size_t)r * 256 + (k - 256)]);
        w2[z] = (_Float16)((k < 256) ? p.Wih2[(size_t)r * 256 + k]
                                     : p.Whh2[(size_t)r * 256 + (k - 256)]);
    }
    _Float16* ws1 = (_Float16*)p.Ws1h;
    for (int z = i0; z < 48 * 2048; z += stride) {           // Ws1: [256 j][384 k]
        int c = z >> 11, rem = z & 2047, j = rem >> 3, lane = rem & 7;
        int k = c * 8 + lane;
        ws1[z] = (_Float16)p.Ws1[(size_t)j * 384 + k];
    }
    for (int z = i0; z < 3072; z += stride) {                // bih+bhh fused
        int l = z >> 10, r = z & 1023;
        const float* bi = l == 0 ? p.bih0 : l == 1 ? p.bih1 : p.bih2;
        const float* bh = l == 0 ? p.bhh0 : l == 1 ? p.bhh1 : p.bhh2;
        p.bsum[z] = bi[r] + bh[r];
    }
    for (int z = i0; z < 256 * 128; z += stride) {           // WqT4 [k4][128][4] fp32
        int k = z >> 7, q = z & 127;
        p.WqT4[((size_t)(k >> 2) * 128 + q) * 4 + (k & 3)] = p.Wq[(size_t)q * HID + k];
    }
    for (int z = i0; z < 256 * VDNUM; z += stride) {         // Ws2T [k][33] fp32
        int k = z / VDNUM, v = z - k * VDNUM;
        p.Ws2T[(size_t)k * VDNUM + v] = p.Ws2[(size_t)v * HID + k];
    }
}

#define DOT8(C, xx, off) \
    a0 += (float)C.h[0] * xx[off+0] + (float)C.h[1] * xx[off+1] \
        + (float)C.h[2] * xx[off+2] + (float)C.h[3] * xx[off+3]; \
    a1 += (float)C.h[4] * xx[off+4] + (float)C.h[5] * xx[off+5] \
        + (float)C.h[6] * xx[off+6] + (float)C.h[7] * xx[off+7];

// ---------------------------------------------------------------------------
// LSTM matvec: thread owns gate-row `tid`. Depth-8 chunk software pipeline:
// two live 4-chunk batches (A,B) + distance-2 prefetch (N) keeps 128 B/thread
// (~128 KB/CU) in flight -> weight stream latency-covered. Named registers
// only (no runtime-indexed arrays -> no scratch). x from LDS broadcast.
// ---------------------------------------------------------------------------
template<int NCH>  // chunks of 8 halves: 48 (L0) or 64 (L1/L2); multiple of 4
__device__ __forceinline__ float matvec_h8(const unsigned short* W, int tid, const float* x)
{
    const uint4e* w = (const uint4e*)W + tid;    // chunk stride = 1024 uint4e
    H8 A0, A1, A2, A3, B0, B1, B2, B3;
    A0.u = w[0];    A1.u = w[1024]; A2.u = w[2048]; A3.u = w[3072];
    B0.u = w[4096]; B1.u = w[5120]; B2.u = w[6144]; B3.u = w[7168];
    float a0 = 0.f, a1 = 0.f;
    for (int c = 0; c < NCH; c += 4) {
        H8 N0, N1, N2, N3;
        const size_t base = (size_t)(c + 8) * 1024;   // pad chunks absorb overrun
        N0.u = w[base]; N1.u = w[base + 1024]; N2.u = w[base + 2048]; N3.u = w[base + 3072];
        const float* xx = x + c * 8;
        DOT8(A0, xx, 0) DOT8(A1, xx, 8) DOT8(A2, xx, 16) DOT8(A3, xx, 24)
        A0 = B0; A1 = B1; A2 = B2; A3 = B3;
        B0 = N0; B1 = N1; B2 = N2; B3 = N3;
    }
    return a0 + a1;
}

// ---------------------------------------------------------------------------
// Persistent per-batch-element kernel: 64 blocks x 1024 threads, one block
// per b, entire 220-step recurrence in-block, ZERO device-scope sync (round-5
// lesson: agent fences invalidate L2 and destroy weight residency).
// fp16 weights + depth-8 prefetch; key/val/outputs non-temporal.
// ---------------------------------------------------------------------------
__global__ __launch_bounds__(1024, 4) void speller(P p)
{
    __shared__ float h[3][HID], c[3][HID], ctx[CTXD];
    __shared__ float xh0[512];            // L0 input [ctx 128 | h0 256]; MLP feat [h2|ctx]
    __shared__ float xh12[512];           // LSTM L1/L2 input [h_prev_layer | h_own_old]
    __shared__ float gacc[1024];
    __shared__ float qry[QDIM];
    __shared__ float s_sc[2048];          // energies -> p -> scores
    __shared__ float red[16][CTXD];
    __shared__ float hid[HID];
    __shared__ float predp[VDNUM * 8];
    __shared__ float predv[VDNUM];
    __shared__ float wred[16];
    __shared__ float bcast;
    __shared__ int   chr;

    const int b   = blockIdx.x;
    const int tid = threadIdx.x;
    const int T   = p.T;
    const int n   = p.seqs[b];

    if (tid < HID) {
        #pragma unroll
        for (int l = 0; l < 3; ++l) { h[l][tid] = p.h0[l * HID + tid]; c[l][tid] = p.c0[l * HID + tid]; }
    }
    if (tid < CTXD) ctx[tid] = p.con[tid];
    if (tid == 0)   chr = 0;
    __syncthreads();

    for (int s = 0; s < p.S; ++s) {
        // ---- build L0 input: [ctx | h0_old] (embed part comes from Ep) ----
        if (tid < 128)      xh0[tid] = ctx[tid];
        else if (tid < 384) xh0[tid] = h[0][tid - 128];
        __syncthreads();

        // ---- L0 (K=384, 48 chunks) + Ep lookup ----
        gacc[tid] = p.bsum[tid] + p.Ep[(size_t)chr * 1024 + tid]
                  + matvec_h8<48>(p.WH0, tid, xh0);
        __syncthreads();
        if (tid < HID) {   // gate order i,f,g,o
            float gi = gacc[tid], gf = gacc[256 + tid], gg = gacc[512 + tid], go = gacc[768 + tid];
            float cn = sigf(gf) * c[0][tid] + sigf(gi) * tanhf(gg);
            c[0][tid] = cn;
            float hn = sigf(go) * tanhf(cn);
            h[0][tid] = hn;
            xh12[tid] = hn; xh12[256 + tid] = h[1][tid];
        }
        __syncthreads();

        // ---- L1 (K=512, 64 chunks) ----
        gacc[tid] = p.bsum[1024 + tid] + matvec_h8<64>(p.WH1, tid, xh12);
        __syncthreads();
        if (tid < HID) {
            float gi = gacc[tid], gf = gacc[256 + tid], gg = gacc[512 + tid], go = gacc[768 + tid];
            float cn = sigf(gf) * c[1][tid] + sigf(gi) * tanhf(gg);
            c[1][tid] = cn;
            float hn = sigf(go) * tanhf(cn);
            h[1][tid] = hn;
            xh12[tid] = hn; xh12[256 + tid] = h[2][tid];
        }
        __syncthreads();

        // ---- L2 (K=512, 64 chunks) ----
        gacc[tid] = p.bsum[2048 + tid] + matvec_h8<64>(p.WH2, tid, xh12);
        __syncthreads();
        if (tid < HID) {
            float gi = gacc[tid], gf = gacc[256 + tid], gg = gacc[512 + tid], go = gacc[768 + tid];
            float cn = sigf(gf) * c[2][tid] + sigf(gi) * tanhf(gg);
            c[2][tid] = cn;
            h[2][tid] = sigf(go) * tanhf(cn);
        }
        __syncthreads();

        // ---- query = h2 @ Wq^T + bq (fp32, 8 k-chunks x 128 q) ----
        {
            const int q = tid & 127, ch = tid >> 7;
            const float4e* w = (const float4e*)p.WqT4 + q;
            float a = 0;
            #pragma unroll
            for (int i = 0; i < 8; ++i) {
                int k4 = ch * 8 + i;
                float4e wv = w[(size_t)k4 * 128];
                const float* x = &h[2][k4 * 4];
                a += x[0] * wv.x + x[1] * wv.y + x[2] * wv.z + x[3] * wv.w;
            }
            gacc[ch * 128 + q] = a;
        }
        __syncthreads();
        if (tid < QDIM) {
            float a = p.bq[tid];
            #pragma unroll
            for (int i = 0; i < 8; ++i) a += gacc[i * 128 + tid];
            qry[tid] = a;
        }
        __syncthreads();

        // ---- energy over t<n + max (non-temporal key reads) ----
        float m = -INFINITY;
        for (int t = tid; t < T; t += 1024) {
            float a = 0.f;
            if (t < n) {
                const float* kp = p.key + (size_t)b * QDIM * T + t;
                float a0 = 0, a1 = 0;
                #pragma unroll 4
                for (int q = 0; q < QDIM; q += 2) {
                    a0 += qry[q]     * __builtin_nontemporal_load(kp + (size_t)q * T);
                    a1 += qry[q + 1] * __builtin_nontemporal_load(kp + (size_t)(q + 1) * T);
                }
                a = a0 + a1;
                m = fmaxf(m, a);
            }
            s_sc[t] = a;
        }
        #pragma unroll
        for (int off = 32; off; off >>= 1) m = fmaxf(m, __shfl_xor(m, off));
        if ((tid & 63) == 0) wred[tid >> 6] = m;
        __syncthreads();
        if (tid == 0) {
            float r = wred[0];
            #pragma unroll
            for (int i = 1; i < 16; ++i) r = fmaxf(r, wred[i]);
            bcast = r;
        }
        __syncthreads();
        m = bcast;

        // ---- exp + sum ----
        float z = 0.f;
        for (int t = tid; t < T; t += 1024) {
            float pv = 0.f;
            if (t < n) { pv = expf(s_sc[t] - m); z += pv; }
            s_sc[t] = pv;
        }
        #pragma unroll
        for (int off = 32; off; off >>= 1) z += __shfl_xor(z, off);
        if ((tid & 63) == 0) wred[tid >> 6] = z;
        __syncthreads();
        if (tid == 0) {
            float r = 0.f;
            #pragma unroll
            for (int i = 0; i < 16; ++i) r += wred[i];
            bcast = r;
        }
        __syncthreads();
        const float Z = bcast;

        // ---- scores out (zeros beyond n; masked+renorm algebra) ----
        float* so = p.outS + ((size_t)b * p.S + s) * T;
        for (int t = tid; t < T; t += 1024) {
            float sc = s_sc[t] / Z;
            s_sc[t] = sc;
            __builtin_nontemporal_store(sc, so + t);
        }
        __syncthreads();

        // ---- ctx = sum_{t<n} score[t] * val[b][t][:] (non-temporal val) ----
        {
            const int tg = tid >> 5, cq = tid & 31;
            const float4e* v4 = (const float4e*)p.val + (size_t)b * T * 32 + cq;
            float ax = 0, ay = 0, az = 0, aw = 0;
            for (int t = tg; t < n; t += 32) {
                float   sv = s_sc[t];
                float4e vv = __builtin_nontemporal_load(v4 + (size_t)t * 32);
                ax += sv * vv.x; ay += sv * vv.y; az += sv * vv.z; aw += sv * vv.w;
            }
            ax += __shfl_xor(ax, 32); ay += __shfl_xor(ay, 32);
            az += __shfl_xor(az, 32); aw += __shfl_xor(aw, 32);
            if ((tid & 63) < 32) {
                const int w = tid >> 6;
                red[w][cq * 4 + 0] = ax; red[w][cq * 4 + 1] = ay;
                red[w][cq * 4 + 2] = az; red[w][cq * 4 + 3] = aw;
            }
        }
        __syncthreads();
        if (tid < CTXD) {
            float a = 0.f;
            #pragma unroll
            for (int w = 0; w < 16; ++w) a += red[w][tid];
            ctx[tid] = a;
            xh0[256 + tid] = a;          // feat = [h2 | ctx_new]
        }
        if (tid < HID) xh0[tid] = h[2][tid];
        __syncthreads();

        // ---- MLP1: hid = relu(feat @ Ws1^T + bs1), fp16 weights + prefetch ----
        {
            const int j = tid & 255, ch = tid >> 8;
            const uint4e* w = (const uint4e*)p.Ws1h + (size_t)(ch * 12) * 256 + j;
            H8 cc; cc.u = w[0];
            float a = 0.f;
            #pragma unroll 2
            for (int u = 0; u < 12; ++u) {
                H8 nx; nx.u = w[(size_t)(u + 1) * 256];   // pad chunk absorbs overrun
                const float* x = xh0 + (ch * 12 + u) * 8;
                a += (float)cc.h[0] * x[0] + (float)cc.h[1] * x[1]
                   + (float)cc.h[2] * x[2] + (float)cc.h[3] * x[3]
                   + (float)cc.h[4] * x[4] + (float)cc.h[5] * x[5]
                   + (float)cc.h[6] * x[6] + (float)cc.h[7] * x[7];
                cc = nx;
            }
            gacc[ch * 256 + j] = a;
        }
        __syncthreads();
        if (tid < HID)
            hid[tid] = fmaxf(p.bs1[tid] + ((gacc[tid] + gacc[256 + tid]) + (gacc[512 + tid] + gacc[768 + tid])), 0.f);
        __syncthreads();

        // ---- predict = hid @ Ws2^T + bs2 (fp32); argmax feedback ----
        if (tid < VDNUM * 8) {
            const int v = tid >> 3, oct = tid & 7;
            const float* w2 = p.Ws2T + (size_t)oct * 32 * VDNUM + v;
            float a = 0.f;
            #pragma unroll 8
            for (int k = 0; k < 32; ++k) a += hid[oct * 32 + k] * w2[(size_t)k * VDNUM];
            predp[v * 8 + oct] = a;
        }
        __syncthreads();
        if (tid < VDNUM) {
            float a = p.bs2[tid];
            #pragma unroll
            for (int o = 0; o < 8; ++o) a += predp[tid * 8 + o];
            __builtin_nontemporal_store(a, p.outP + ((size_t)b * p.S + s) * VDNUM + tid);
            predv[tid] = a;
        }
        __syncthreads();
        if (tid == 0) {   // first-occurrence argmax (strict >)
            int best = 0; float bv = predv[0];
            for (int v = 1; v < VDNUM; ++v) if (predv[v] > bv) { bv = predv[v]; best = v; }
            chr = best;
        }
        __syncthreads();
    }
}

extern "C" void kernel_launch(void* const* d_in, const int* in_sizes, int n_in,
                              void* d_out, int out_size, void* d_ws, size_t ws_size,
                              hipStream_t stream)
{
    P p;
    p.seqs  = (const int*)  d_in[0];
    p.key   = (const float*)d_in[1];
    p.val   = (const float*)d_in[2];
    p.embed = (const float*)d_in[4];
    p.Wih0  = (const float*)d_in[5];  p.Whh0 = (const float*)d_in[6];
    p.bih0  = (const float*)d_in[7];  p.bhh0 = (const float*)d_in[8];
    p.Wih1  = (const float*)d_in[9];  p.Whh1 = (const float*)d_in[10];
    p.bih1  = (const float*)d_in[11]; p.bhh1 = (const float*)d_in[12];
    p.Wih2  = (const float*)d_in[13]; p.Whh2 = (const float*)d_in[14];
    p.bih2  = (const float*)d_in[15]; p.bhh2 = (const float*)d_in[16];
    p.Wq    = (const float*)d_in[17]; p.bq   = (const float*)d_in[18];
    p.Ws1   = (const float*)d_in[19]; p.bs1  = (const float*)d_in[20];
    p.Ws2   = (const float*)d_in[21]; p.bs2  = (const float*)d_in[22];
    p.h0    = (const float*)d_in[23];
    p.c0    = (const float*)d_in[24];
    p.con   = (const float*)d_in[25];

    const int B = in_sizes[0];                  // 64
    p.T = in_sizes[1] / (B * QDIM);             // 2048
    p.S = in_sizes[3] / B;                      // 220

    // workspace layout (bytes; 16B-aligned). fp16 weights with 8 pad chunks.
    char* ws = (char*)d_ws;
    p.WH0  = (unsigned short*)(ws + 0);          // 56 chunks * 8192 halves =   917,504 B
    p.WH1  = (unsigned short*)(ws + 917504);     // 72 * 8192 halves       = 1,179,648 B
    p.WH2  = (unsigned short*)(ws + 2097152);    // 1,179,648 B
    p.Ws1h = (unsigned short*)(ws + 3276800);    // 49 * 2048 halves       =   200,704 B
    p.bsum = (float*)(ws + 3477504);             // 3072 f                 =    12,288 B
    p.WqT4 = (float*)(ws + 3489792);             // 32768 f                =   131,072 B
    p.Ws2T = (float*)(ws + 3620864);             // 8448 f                 =    33,792 B
    p.Ep   = (float*)(ws + 3654656);             // 33*1024 f              =   135,168 B

    p.outS = (float*)d_out;
    p.outP = p.outS + (size_t)B * p.S * p.T;

    prep<<<1024, 256, 0, stream>>>(p);
    speller<<<B, 1024, 0, stream>>>(p);
}

// Round 10
// 18121.848 us; speedup vs baseline: 3.0227x; 1.1118x over previous
//
#include <hip/hip_runtime.h>
#include <cstddef>

#define HID   256
#define CTXD  128
#define QDIM  128
#define VDNUM 33

typedef float  float4e __attribute__((ext_vector_type(4)));
typedef unsigned int uint4e __attribute__((ext_vector_type(4)));

__device__ __forceinline__ float sigf(float x) { return 1.f / (1.f + expf(-x)); }

union H8 { uint4e u; _Float16 h[8]; };

struct P {
    const int*   seqs;
    const float* key; const float* val; const float* embed;
    const float* Wih0; const float* Whh0; const float* bih0; const float* bhh0;
    const float* Wih1; const float* Whh1; const float* bih1; const float* bhh1;
    const float* Wih2; const float* Whh2; const float* bih2; const float* bhh2;
    const float* Wq;  const float* bq;
    const float* Ws1; const float* bs1;
    const float* Ws2; const float* bs2;
    const float* h0; const float* c0; const float* con;
    unsigned short* WH0; unsigned short* WH1; unsigned short* WH2;  // fp16 LSTM weights
    unsigned short* Ws1h;                                           // fp16 MLP1 weights
    float* bsum; float* WqT4; float* Ws2T; float* Ep;
    float* outS; float* outP;
    int S, T;
};

// ---------------------------------------------------------------------------
// Weight repack to fp16, chunk-of-8 layout: WH[(c*1024 + r)*8 + j] holds
// w[row r][k = c*8+j]. Pad chunks (to 64/80 totals) absorb the depth-12
// prefetch overrun (loaded, never used in arithmetic). L0's embed columns are
// folded into Ep[char][row] (exact fp32) -> L0 streams K=384 [ctx|h] only.
// ---------------------------------------------------------------------------
__global__ void prep(P p)
{
    const int stride = gridDim.x * blockDim.x;
    const int i0 = blockIdx.x * blockDim.x + threadIdx.x;

    // Ep[c][r] = sum_k embed[c][k] * Wih0[r][k], k<256 (exact fp32)
    for (int z = i0; z < VDNUM * 1024; z += stride) {
        int c = z >> 10, r = z & 1023;
        const float* w = p.Wih0 + (size_t)r * 384;
        const float* e = p.embed + c * HID;
        float a = 0.f;
        #pragma unroll 8
        for (int k = 0; k < HID; ++k) a += e[k] * w[k];
        p.Ep[z] = a;
    }

    _Float16* w0 = (_Float16*)p.WH0;
    for (int z = i0; z < 48 * 8192; z += stride) {           // L0: K=384 = [ctx|h]
        int c = z >> 13, rem = z & 8191, r = rem >> 3, j = rem & 7;
        int k = c * 8 + j;
        float v = (k < 128) ? p.Wih0[(size_t)r * 384 + 256 + k]   // ctx cols
                            : p.Whh0[(size_t)r * 256 + (k - 128)];
        w0[z] = (_Float16)v;
    }
    _Float16* w1 = (_Float16*)p.WH1;
    _Float16* w2 = (_Float16*)p.WH2;
    for (int z = i0; z < 64 * 8192; z += stride) {           // L1,L2: K=512
        int c = z >> 13, rem = z & 8191, r = rem >> 3, j = rem & 7;
        int k = c * 8 + j;
        w1[z] = (_Float16)((k < 256) ? p.Wih1[(size_t)r * 256 + k]
                                     : p.Whh1[(size_t)r * 256 + (k - 256)]);
        w2[z] = (_Float16)((k < 256) ? p.Wih2[(size_t)r * 256 + k]
                                     : p.Whh2[(size_t)r * 256 + (k - 256)]);
    }
    _Float16* ws1 = (_Float16*)p.Ws1h;
    for (int z = i0; z < 48 * 2048; z += stride) {           // Ws1: [256 j][384 k]
        int c = z >> 11, rem = z & 2047, j = rem >> 3, lane = rem & 7;
        int k = c * 8 + lane;
        ws1[z] = (_Float16)p.Ws1[(size_t)j * 384 + k];
    }
    for (int z = i0; z < 3072; z += stride) {                // bih+bhh fused
        int l = z >> 10, r = z & 1023;
        const float* bi = l == 0 ? p.bih0 : l == 1 ? p.bih1 : p.bih2;
        const float* bh = l == 0 ? p.bhh0 : l == 1 ? p.bhh1 : p.bhh2;
        p.bsum[z] = bi[r] + bh[r];
    }
    for (int z = i0; z < 256 * 128; z += stride) {           // WqT4 [k4][128][4] fp32
        int k = z >> 7, q = z & 127;
        p.WqT4[((size_t)(k >> 2) * 128 + q) * 4 + (k & 3)] = p.Wq[(size_t)q * HID + k];
    }
    for (int z = i0; z < 256 * VDNUM; z += stride) {         // Ws2T [k][33] fp32
        int k = z / VDNUM, v = z - k * VDNUM;
        p.Ws2T[(size_t)k * VDNUM + v] = p.Ws2[(size_t)v * HID + k];
    }
}

#define DOT8(C, xx, off) \
    a0 += (float)C.h[0] * xx[off+0] + (float)C.h[1] * xx[off+1] \
        + (float)C.h[2] * xx[off+2] + (float)C.h[3] * xx[off+3]; \
    a1 += (float)C.h[4] * xx[off+4] + (float)C.h[5] * xx[off+5] \
        + (float)C.h[6] * xx[off+6] + (float)C.h[7] * xx[off+7];

// ---------------------------------------------------------------------------
// LSTM matvec: thread owns gate-row `tid`. Depth-12 chunk software pipeline
// (A,B,C live 4-chunk batches + distance-3 prefetch N): 192 B/thread in
// flight (~192 KB/CU) -> L2/L3 latency covered at 16 waves/CU. Named
// registers only. x from LDS broadcast.
// ---------------------------------------------------------------------------
template<int NCH>  // chunks of 8 halves: 48 (L0) or 64 (L1/L2); multiple of 4
__device__ __forceinline__ float matvec_h8(const unsigned short* W, int tid, const float* x)
{
    const uint4e* w = (const uint4e*)W + tid;    // chunk stride = 1024 uint4e
    H8 A0, A1, A2, A3, B0, B1, B2, B3, C0, C1, C2, C3;
    A0.u = w[0];    A1.u = w[1024]; A2.u = w[2048];  A3.u = w[3072];
    B0.u = w[4096]; B1.u = w[5120]; B2.u = w[6144];  B3.u = w[7168];
    C0.u = w[8192]; C1.u = w[9216]; C2.u = w[10240]; C3.u = w[11264];
    float a0 = 0.f, a1 = 0.f;
    for (int c = 0; c < NCH; c += 4) {
        H8 N0, N1, N2, N3;
        const size_t base = (size_t)(c + 12) * 1024;   // pad chunks absorb overrun
        N0.u = w[base]; N1.u = w[base + 1024]; N2.u = w[base + 2048]; N3.u = w[base + 3072];
        const float* xx = x + c * 8;
        DOT8(A0, xx, 0) DOT8(A1, xx, 8) DOT8(A2, xx, 16) DOT8(A3, xx, 24)
        A0 = B0; A1 = B1; A2 = B2; A3 = B3;
        B0 = C0; B1 = C1; B2 = C2; B3 = C3;
        C0 = N0; C1 = N1; C2 = N2; C3 = N3;
    }
    return a0 + a1;
}

// ---------------------------------------------------------------------------
// Persistent per-batch-element kernel: 64 blocks x 1024 threads, one block
// per b, entire 220-step recurrence in-block, ZERO device-scope sync.
// key/val are NORMAL loads (L3-resident across steps; round-8 lesson: nt =
// no-allocate forced them to HBM every step). nt only on write-once outputs.
// ---------------------------------------------------------------------------
__global__ __launch_bounds__(1024, 4) void speller(P p)
{
    __shared__ float h[3][HID], c[3][HID], ctx[CTXD];
    __shared__ float xh0[512];            // L0 input [ctx 128 | h0 256]; MLP feat [h2|ctx]
    __shared__ float xh12[512];           // LSTM L1/L2 input [h_prev_layer | h_own_old]
    __shared__ float gacc[1024];
    __shared__ float qry[QDIM];
    __shared__ float s_sc[2048];          // energies -> p -> scores
    __shared__ float4e ep[4][256];        // energy q-group partials (16 KB)
    __shared__ float red[16][CTXD];
    __shared__ float hid[HID];
    __shared__ float predp[VDNUM * 8];
    __shared__ float predv[VDNUM];
    __shared__ float wred[16];
    __shared__ float bcast;
    __shared__ int   chr;

    const int b   = blockIdx.x;
    const int tid = threadIdx.x;
    const int T   = p.T;
    const int T4  = T >> 2;
    const int n   = p.seqs[b];

    if (tid < HID) {
        #pragma unroll
        for (int l = 0; l < 3; ++l) { h[l][tid] = p.h0[l * HID + tid]; c[l][tid] = p.c0[l * HID + tid]; }
    }
    if (tid < CTXD) ctx[tid] = p.con[tid];
    if (tid == 0)   chr = 0;
    __syncthreads();

    for (int s = 0; s < p.S; ++s) {
        // ---- build L0 input: [ctx | h0_old] (embed part from Ep) ----
        if (tid < 128)      xh0[tid] = ctx[tid];
        else if (tid < 384) xh0[tid] = h[0][tid - 128];
        __syncthreads();

        // ---- L0 (K=384, 48 chunks) + Ep lookup ----
        gacc[tid] = p.bsum[tid] + p.Ep[(size_t)chr * 1024 + tid]
                  + matvec_h8<48>(p.WH0, tid, xh0);
        __syncthreads();
        if (tid < HID) {   // gate order i,f,g,o
            float gi = gacc[tid], gf = gacc[256 + tid], gg = gacc[512 + tid], go = gacc[768 + tid];
            float cn = sigf(gf) * c[0][tid] + sigf(gi) * tanhf(gg);
            c[0][tid] = cn;
            float hn = sigf(go) * tanhf(cn);
            h[0][tid] = hn;
            xh12[tid] = hn; xh12[256 + tid] = h[1][tid];
        }
        __syncthreads();

        // ---- L1 (K=512, 64 chunks) ----
        gacc[tid] = p.bsum[1024 + tid] + matvec_h8<64>(p.WH1, tid, xh12);
        __syncthreads();
        if (tid < HID) {
            float gi = gacc[tid], gf = gacc[256 + tid], gg = gacc[512 + tid], go = gacc[768 + tid];
            float cn = sigf(gf) * c[1][tid] + sigf(gi) * tanhf(gg);
            c[1][tid] = cn;
            float hn = sigf(go) * tanhf(cn);
            h[1][tid] = hn;
            xh12[tid] = hn; xh12[256 + tid] = h[2][tid];
        }
        __syncthreads();

        // ---- L2 (K=512, 64 chunks) ----
        gacc[tid] = p.bsum[2048 + tid] + matvec_h8<64>(p.WH2, tid, xh12);
        __syncthreads();
        if (tid < HID) {
            float gi = gacc[tid], gf = gacc[256 + tid], gg = gacc[512 + tid], go = gacc[768 + tid];
            float cn = sigf(gf) * c[2][tid] + sigf(gi) * tanhf(gg);
            c[2][tid] = cn;
            h[2][tid] = sigf(go) * tanhf(cn);
        }
        __syncthreads();

        // ---- query = h2 @ Wq^T + bq (fp32, 8 k-chunks x 128 q) ----
        {
            const int q = tid & 127, ch = tid >> 7;
            const float4e* w = (const float4e*)p.WqT4 + q;
            float a = 0;
            #pragma unroll
            for (int i = 0; i < 8; ++i) {
                int k4 = ch * 8 + i;
                float4e wv = w[(size_t)k4 * 128];
                const float* x = &h[2][k4 * 4];
                a += x[0] * wv.x + x[1] * wv.y + x[2] * wv.z + x[3] * wv.w;
            }
            gacc[ch * 128 + q] = a;
        }
        __syncthreads();
        if (tid < QDIM) {
            float a = p.bq[tid];
            #pragma unroll
            for (int i = 0; i < 8; ++i) a += gacc[i * 128 + tid];
            qry[tid] = a;
        }
        __syncthreads();

        // ---- energy: 2 passes over t-halves; thread = (t4 slot, q-group) ----
        // 32 independent float4 loads/thread/pass; 4-way LDS reduce.
        {
            const int tl = tid & 255, qg = tid >> 8;    // qg wave-uniform
            #pragma unroll
            for (int half = 0; half < 2; ++half) {
                const int t0 = half << 10;
                float4e e = {0.f, 0.f, 0.f, 0.f};
                if (t0 < n) {
                    const float4e* k4 = (const float4e*)p.key + (size_t)b * QDIM * T4
                                      + (t0 >> 2) + tl;
                    const int q0 = qg * 32;
                    #pragma unroll 8
                    for (int qq = 0; qq < 32; ++qq) {
                        float4e kv = k4[(size_t)(q0 + qq) * T4];
                        e += qry[q0 + qq] * kv;
                    }
                }
                ep[qg][tl] = e;
                __syncthreads();
                if (tid < 256 && t0 < n) {
                    float4e r = (ep[0][tid] + ep[1][tid]) + (ep[2][tid] + ep[3][tid]);
                    ((float4e*)s_sc)[(t0 >> 2) + tid] = r;
                }
                __syncthreads();
            }
        }

        // ---- max over t<n ----
        float m = -INFINITY;
        for (int t = tid; t < n; t += 1024) m = fmaxf(m, s_sc[t]);
        #pragma unroll
        for (int off = 32; off; off >>= 1) m = fmaxf(m, __shfl_xor(m, off));
        if ((tid & 63) == 0) wred[tid >> 6] = m;
        __syncthreads();
        if (tid == 0) {
            float r = wred[0];
            #pragma unroll
            for (int i = 1; i < 16; ++i) r = fmaxf(r, wred[i]);
            bcast = r;
        }
        __syncthreads();
        m = bcast;

        // ---- exp + sum (writes 0 beyond n, overwriting stale LDS) ----
        float z = 0.f;
        for (int t = tid; t < T; t += 1024) {
            float pv = 0.f;
            if (t < n) { pv = expf(s_sc[t] - m); z += pv; }
            s_sc[t] = pv;
        }
        #pragma unroll
        for (int off = 32; off; off >>= 1) z += __shfl_xor(z, off);
        if ((tid & 63) == 0) wred[tid >> 6] = z;
        __syncthreads();
        if (tid == 0) {
            float r = 0.f;
            #pragma unroll
            for (int i = 0; i < 16; ++i) r += wred[i];
            bcast = r;
        }
        __syncthreads();
        const float Z = bcast;

        // ---- scores out (zeros beyond n; masked+renorm algebra) ----
        float* so = p.outS + ((size_t)b * p.S + s) * T;
        for (int t = tid; t < T; t += 1024) {
            float sc = s_sc[t] / Z;
            s_sc[t] = sc;
            __builtin_nontemporal_store(sc, so + t);
        }
        __syncthreads();

        // ---- ctx = sum_{t<n} score[t] * val[b][t][:] ----
        {
            const int tg = tid >> 5, cq = tid & 31;
            const float4e* v4 = (const float4e*)p.val + (size_t)b * T * 32 + cq;
            float ax = 0, ay = 0, az = 0, aw = 0;
            #pragma unroll 4
            for (int t = tg; t < n; t += 32) {
                float   sv = s_sc[t];
                float4e vv = v4[(size_t)t * 32];
                ax += sv * vv.x; ay += sv * vv.y; az += sv * vv.z; aw += sv * vv.w;
            }
            ax += __shfl_xor(ax, 32); ay += __shfl_xor(ay, 32);
            az += __shfl_xor(az, 32); aw += __shfl_xor(aw, 32);
            if ((tid & 63) < 32) {
                const int w = tid >> 6;
                red[w][cq * 4 + 0] = ax; red[w][cq * 4 + 1] = ay;
                red[w][cq * 4 + 2] = az; red[w][cq * 4 + 3] = aw;
            }
        }
        __syncthreads();
        if (tid < CTXD) {
            float a = 0.f;
            #pragma unroll
            for (int w = 0; w < 16; ++w) a += red[w][tid];
            ctx[tid] = a;
            xh0[256 + tid] = a;          // feat = [h2 | ctx_new]
        }
        if (tid < HID) xh0[tid] = h[2][tid];
        __syncthreads();

        // ---- MLP1: hid = relu(feat @ Ws1^T + bs1), fp16 weights + prefetch ----
        {
            const int j = tid & 255, ch = tid >> 8;
            const uint4e* w = (const uint4e*)p.Ws1h + (size_t)(ch * 12) * 256 + j;
            H8 cc; cc.u = w[0];
            float a = 0.f;
            #pragma unroll 2
            for (int u = 0; u < 12; ++u) {
                H8 nx; nx.u = w[(size_t)(u + 1) * 256];   // pad chunk absorbs overrun
                const float* x = xh0 + (ch * 12 + u) * 8;
                a += (float)cc.h[0] * x[0] + (float)cc.h[1] * x[1]
                   + (float)cc.h[2] * x[2] + (float)cc.h[3] * x[3]
                   + (float)cc.h[4] * x[4] + (float)cc.h[5] * x[5]
                   + (float)cc.h[6] * x[6] + (float)cc.h[7] * x[7];
                cc = nx;
            }
            gacc[ch * 256 + j] = a;
        }
        __syncthreads();
        if (tid < HID)
            hid[tid] = fmaxf(p.bs1[tid] + ((gacc[tid] + gacc[256 + tid]) + (gacc[512 + tid] + gacc[768 + tid])), 0.f);
        __syncthreads();

        // ---- predict = hid @ Ws2^T + bs2 (fp32); argmax feedback ----
        if (tid < VDNUM * 8) {
            const int v = tid >> 3, oct = tid & 7;
            const float* w2 = p.Ws2T + (size_t)oct * 32 * VDNUM + v;
            float a = 0.f;
            #pragma unroll 8
            for (int k = 0; k < 32; ++k) a += hid[oct * 32 + k] * w2[(size_t)k * VDNUM];
            predp[v * 8 + oct] = a;
        }
        __syncthreads();
        if (tid < VDNUM) {
            float a = p.bs2[tid];
            #pragma unroll
            for (int o = 0; o < 8; ++o) a += predp[tid * 8 + o];
            __builtin_nontemporal_store(a, p.outP + ((size_t)b * p.S + s) * VDNUM + tid);
            predv[tid] = a;
        }
        __syncthreads();
        if (tid == 0) {   // first-occurrence argmax (strict >)
            int best = 0; float bv = predv[0];
            for (int v = 1; v < VDNUM; ++v) if (predv[v] > bv) { bv = predv[v]; best = v; }
            chr = best;
        }
        __syncthreads();
    }
}

extern "C" void kernel_launch(void* const* d_in, const int* in_sizes, int n_in,
                              void* d_out, int out_size, void* d_ws, size_t ws_size,
                              hipStream_t stream)
{
    P p;
    p.seqs  = (const int*)  d_in[0];
    p.key   = (const float*)d_in[1];
    p.val   = (const float*)d_in[2];
    p.embed = (const float*)d_in[4];
    p.Wih0  = (const float*)d_in[5];  p.Whh0 = (const float*)d_in[6];
    p.bih0  = (const float*)d_in[7];  p.bhh0 = (const float*)d_in[8];
    p.Wih1  = (const float*)d_in[9];  p.Whh1 = (const float*)d_in[10];
    p.bih1  = (const float*)d_in[11]; p.bhh1 = (const float*)d_in[12];
    p.Wih2  = (const float*)d_in[13]; p.Whh2 = (const float*)d_in[14];
    p.bih2  = (const float*)d_in[15]; p.bhh2 = (const float*)d_in[16];
    p.Wq    = (const float*)d_in[17]; p.bq   = (const float*)d_in[18];
    p.Ws1   = (const float*)d_in[19]; p.bs1  = (const float*)d_in[20];
    p.Ws2   = (const float*)d_in[21]; p.bs2  = (const float*)d_in[22];
    p.h0    = (const float*)d_in[23];
    p.c0    = (const float*)d_in[24];
    p.con   = (const float*)d_in[25];

    const int B = in_sizes[0];                  // 64
    p.T = in_sizes[1] / (B * QDIM);             // 2048
    p.S = in_sizes[3] / B;                      // 220

    // workspace layout (bytes; 16B-aligned). fp16 weights padded for depth-12.
    char* ws = (char*)d_ws;
    p.WH0  = (unsigned short*)(ws + 0);          // 64 chunks * 8192 halves = 1,048,576 B
    p.WH1  = (unsigned short*)(ws + 1048576);    // 80 * 8192 halves       = 1,310,720 B
    p.WH2  = (unsigned short*)(ws + 2359296);    // 1,310,720 B
    p.Ws1h = (unsigned short*)(ws + 3670016);    // 49 * 2048 halves       =   200,704 B
    p.bsum = (float*)(ws + 3870720);             // 3072 f                 =    12,288 B
    p.WqT4 = (float*)(ws + 3883008);             // 32768 f                =   131,072 B
    p.Ws2T = (float*)(ws + 4014080);             // 8448 f                 =    33,792 B
    p.Ep   = (float*)(ws + 4047872);             // 33*1024 f              =   135,168 B

    p.outS = (float*)d_out;
    p.outP = p.outS + (size_t)B * p.S * p.T;

    prep<<<1024, 256, 0, stream>>>(p);
    speller<<<B, 1024, 0, stream>>>(p);
}

// Round 11
// 17871.831 us; speedup vs baseline: 3.0649x; 1.0140x over previous
//
#include <hip/hip_runtime.h>
#include <cstddef>

#define HID   256
#define CTXD  128
#define QDIM  128
#define VDNUM 33

typedef float  float4e __attribute__((ext_vector_type(4)));
typedef unsigned int uint4e __attribute__((ext_vector_type(4)));
typedef unsigned int uint2e __attribute__((ext_vector_type(2)));

__device__ __forceinline__ float sigf(float x) { return 1.f / (1.f + expf(-x)); }

union H8 { uint4e u; _Float16 h[8]; };
union H4 { uint2e u; _Float16 h[4]; };

struct P {
    const int*   seqs;
    const float* key; const float* val; const float* embed;
    const float* Wih0; const float* Whh0; const float* bih0; const float* bhh0;
    const float* Wih1; const float* Whh1; const float* bih1; const float* bhh1;
    const float* Wih2; const float* Whh2; const float* bih2; const float* bhh2;
    const float* Wq;  const float* bq;
    const float* Ws1; const float* bs1;
    const float* Ws2; const float* bs2;
    const float* h0; const float* c0; const float* con;
    unsigned short* WH0; unsigned short* WH1; unsigned short* WH2;  // fp16 LSTM weights
    unsigned short* Ws1h;                                           // fp16 MLP1 weights
    float* bsum; float* WqT4; float* Ws2T; float* Ep;
    unsigned short* keyh; unsigned short* valh;                     // fp16 key/val copies
    int dokv;
    float* outS; float* outP;
    int S, T;
};

// ---------------------------------------------------------------------------
// One-time repack (every call, deterministic): fp16 LSTM/MLP weights in
// chunk-of-8 layout (pad chunks absorb depth-12 prefetch overrun), Ep embed
// fold (exact fp32), and — when workspace allows — fp16 copies of key/val in
// the SAME layout as the fp32 originals (halves bytes AND 64B-line count of
// the per-step L3 stream, which is per-CU concurrency-limited).
// ---------------------------------------------------------------------------
__global__ void prep(P p)
{
    const int stride = gridDim.x * blockDim.x;
    const int i0 = blockIdx.x * blockDim.x + threadIdx.x;
    const int T = p.T;

    // Ep[c][r] = sum_k embed[c][k] * Wih0[r][k], k<256 (exact fp32)
    for (int z = i0; z < VDNUM * 1024; z += stride) {
        int c = z >> 10, r = z & 1023;
        const float* w = p.Wih0 + (size_t)r * 384;
        const float* e = p.embed + c * HID;
        float a = 0.f;
        #pragma unroll 8
        for (int k = 0; k < HID; ++k) a += e[k] * w[k];
        p.Ep[z] = a;
    }

    _Float16* w0 = (_Float16*)p.WH0;
    for (int z = i0; z < 48 * 8192; z += stride) {           // L0: K=384 = [ctx|h]
        int c = z >> 13, rem = z & 8191, r = rem >> 3, j = rem & 7;
        int k = c * 8 + j;
        float v = (k < 128) ? p.Wih0[(size_t)r * 384 + 256 + k]
                            : p.Whh0[(size_t)r * 256 + (k - 128)];
        w0[z] = (_Float16)v;
    }
    _Float16* w1 = (_Float16*)p.WH1;
    _Float16* w2 = (_Float16*)p.WH2;
    for (int z = i0; z < 64 * 8192; z += stride) {           // L1,L2: K=512
        int c = z >> 13, rem = z & 8191, r = rem >> 3, j = rem & 7;
        int k = c * 8 + j;
        w1[z] = (_Float16)((k < 256) ? p.Wih1[(size_t)r * 256 + k]
                                     : p.Whh1[(size_t)r * 256 + (k - 256)]);
        w2[z] = (_Float16)((k < 256) ? p.Wih2[(size_t)r * 256 + k]
                                     : p.Whh2[(size_t)r * 256 + (k - 256)]);
    }
    _Float16* ws1 = (_Float16*)p.Ws1h;
    for (int z = i0; z < 48 * 2048; z += stride) {           // Ws1: [256 j][384 k]
        int c = z >> 11, rem = z & 2047, j = rem >> 3, lane = rem & 7;
        int k = c * 8 + lane;
        ws1[z] = (_Float16)p.Ws1[(size_t)j * 384 + k];
    }
    for (int z = i0; z < 3072; z += stride) {                // bih+bhh fused
        int l = z >> 10, r = z & 1023;
        const float* bi = l == 0 ? p.bih0 : l == 1 ? p.bih1 : p.bih2;
        const float* bh = l == 0 ? p.bhh0 : l == 1 ? p.bhh1 : p.bhh2;
        p.bsum[z] = bi[r] + bh[r];
    }
    for (int z = i0; z < 256 * 128; z += stride) {           // WqT4 [k4][128][4] fp32
        int k = z >> 7, q = z & 127;
        p.WqT4[((size_t)(k >> 2) * 128 + q) * 4 + (k & 3)] = p.Wq[(size_t)q * HID + k];
    }
    for (int z = i0; z < 256 * VDNUM; z += stride) {         // Ws2T [k][33] fp32
        int k = z / VDNUM, v = z - k * VDNUM;
        p.Ws2T[(size_t)k * VDNUM + v] = p.Ws2[(size_t)v * HID + k];
    }
    if (p.dokv) {
        _Float16* kh = (_Float16*)p.keyh;
        _Float16* vh = (_Float16*)p.valh;
        const int NKV = 64 * QDIM * T;                       // 33.5M each
        for (int z = i0; z < NKV; z += stride) kh[z] = (_Float16)p.key[z];
        for (int z = i0; z < NKV; z += stride) vh[z] = (_Float16)p.val[z];
    }
}

#define DOT8(C, xx, off) \
    a0 += (float)C.h[0] * xx[off+0] + (float)C.h[1] * xx[off+1] \
        + (float)C.h[2] * xx[off+2] + (float)C.h[3] * xx[off+3]; \
    a1 += (float)C.h[4] * xx[off+4] + (float)C.h[5] * xx[off+5] \
        + (float)C.h[6] * xx[off+6] + (float)C.h[7] * xx[off+7];

// ---------------------------------------------------------------------------
// LSTM matvec: thread owns gate-row `tid`. Depth-12 chunk software pipeline
// (A,B,C live batches + distance-3 prefetch): 192 B/thread in flight.
// ---------------------------------------------------------------------------
template<int NCH>
__device__ __forceinline__ float matvec_h8(const unsigned short* W, int tid, const float* x)
{
    const uint4e* w = (const uint4e*)W + tid;
    H8 A0, A1, A2, A3, B0, B1, B2, B3, C0, C1, C2, C3;
    A0.u = w[0];    A1.u = w[1024]; A2.u = w[2048];  A3.u = w[3072];
    B0.u = w[4096]; B1.u = w[5120]; B2.u = w[6144];  B3.u = w[7168];
    C0.u = w[8192]; C1.u = w[9216]; C2.u = w[10240]; C3.u = w[11264];
    float a0 = 0.f, a1 = 0.f;
    for (int c = 0; c < NCH; c += 4) {
        H8 N0, N1, N2, N3;
        const size_t base = (size_t)(c + 12) * 1024;
        N0.u = w[base]; N1.u = w[base + 1024]; N2.u = w[base + 2048]; N3.u = w[base + 3072];
        const float* xx = x + c * 8;
        DOT8(A0, xx, 0) DOT8(A1, xx, 8) DOT8(A2, xx, 16) DOT8(A3, xx, 24)
        A0 = B0; A1 = B1; A2 = B2; A3 = B3;
        B0 = C0; B1 = C1; B2 = C2; B3 = C3;
        C0 = N0; C1 = N1; C2 = N2; C3 = N3;
    }
    return a0 + a1;
}

// ---------------------------------------------------------------------------
// Persistent per-batch-element kernel: 64 blocks x 1024 threads, zero
// device-scope sync. KV16: key/val read as fp16 (converted in-register;
// summation order identical to fp32 path — only operand quantization changes).
// ---------------------------------------------------------------------------
template<bool KV16>
__global__ __launch_bounds__(1024, 4) void speller(P p)
{
    __shared__ float h[3][HID], c[3][HID], ctx[CTXD];
    __shared__ float xh0[512];
    __shared__ float xh12[512];
    __shared__ float gacc[1024];
    __shared__ float qry[QDIM];
    __shared__ float s_sc[2048];
    __shared__ float4e ep[4][256];
    __shared__ float red[16][CTXD];
    __shared__ float hid[HID];
    __shared__ float predp[VDNUM * 8];
    __shared__ float predv[VDNUM];
    __shared__ float wred[16];
    __shared__ float bcast;
    __shared__ int   chr;

    const int b   = blockIdx.x;
    const int tid = threadIdx.x;
    const int T   = p.T;
    const int T4  = T >> 2;
    const int n   = p.seqs[b];

    if (tid < HID) {
        #pragma unroll
        for (int l = 0; l < 3; ++l) { h[l][tid] = p.h0[l * HID + tid]; c[l][tid] = p.c0[l * HID + tid]; }
    }
    if (tid < CTXD) ctx[tid] = p.con[tid];
    if (tid == 0)   chr = 0;
    __syncthreads();

    for (int s = 0; s < p.S; ++s) {
        // ---- build L0 input: [ctx | h0_old] (embed part from Ep) ----
        if (tid < 128)      xh0[tid] = ctx[tid];
        else if (tid < 384) xh0[tid] = h[0][tid - 128];
        __syncthreads();

        // ---- L0 (K=384) + Ep lookup ----
        gacc[tid] = p.bsum[tid] + p.Ep[(size_t)chr * 1024 + tid]
                  + matvec_h8<48>(p.WH0, tid, xh0);
        __syncthreads();
        if (tid < HID) {
            float gi = gacc[tid], gf = gacc[256 + tid], gg = gacc[512 + tid], go = gacc[768 + tid];
            float cn = sigf(gf) * c[0][tid] + sigf(gi) * tanhf(gg);
            c[0][tid] = cn;
            float hn = sigf(go) * tanhf(cn);
            h[0][tid] = hn;
            xh12[tid] = hn; xh12[256 + tid] = h[1][tid];
        }
        __syncthreads();

        // ---- L1 (K=512) ----
        gacc[tid] = p.bsum[1024 + tid] + matvec_h8<64>(p.WH1, tid, xh12);
        __syncthreads();
        if (tid < HID) {
            float gi = gacc[tid], gf = gacc[256 + tid], gg = gacc[512 + tid], go = gacc[768 + tid];
            float cn = sigf(gf) * c[1][tid] + sigf(gi) * tanhf(gg);
            c[1][tid] = cn;
            float hn = sigf(go) * tanhf(cn);
            h[1][tid] = hn;
            xh12[tid] = hn; xh12[256 + tid] = h[2][tid];
        }
        __syncthreads();

        // ---- L2 (K=512) ----
        gacc[tid] = p.bsum[2048 + tid] + matvec_h8<64>(p.WH2, tid, xh12);
        __syncthreads();
        if (tid < HID) {
            float gi = gacc[tid], gf = gacc[256 + tid], gg = gacc[512 + tid], go = gacc[768 + tid];
            float cn = sigf(gf) * c[2][tid] + sigf(gi) * tanhf(gg);
            c[2][tid] = cn;
            h[2][tid] = sigf(go) * tanhf(cn);
        }
        __syncthreads();

        // ---- query = h2 @ Wq^T + bq ----
        {
            const int q = tid & 127, ch = tid >> 7;
            const float4e* w = (const float4e*)p.WqT4 + q;
            float a = 0;
            #pragma unroll
            for (int i = 0; i < 8; ++i) {
                int k4 = ch * 8 + i;
                float4e wv = w[(size_t)k4 * 128];
                const float* x = &h[2][k4 * 4];
                a += x[0] * wv.x + x[1] * wv.y + x[2] * wv.z + x[3] * wv.w;
            }
            gacc[ch * 128 + q] = a;
        }
        __syncthreads();
        if (tid < QDIM) {
            float a = p.bq[tid];
            #pragma unroll
            for (int i = 0; i < 8; ++i) a += gacc[i * 128 + tid];
            qry[tid] = a;
        }
        __syncthreads();

        // ---- energy: 2 passes over t-halves; thread = (t4 slot, q-group) ----
        {
            const int tl = tid & 255, qg = tid >> 8;
            #pragma unroll
            for (int half = 0; half < 2; ++half) {
                const int t0 = half << 10;
                float4e e = {0.f, 0.f, 0.f, 0.f};
                if (t0 < n) {
                    const int q0 = qg * 32;
                    if (KV16) {
                        const uint2e* k2 = (const uint2e*)p.keyh
                            + (((size_t)b * QDIM * T + t0) >> 2) + tl;
                        #pragma unroll 8
                        for (int qq = 0; qq < 32; ++qq) {
                            H4 kv; kv.u = k2[(size_t)(q0 + qq) * (T >> 2)];
                            float qv = qry[q0 + qq];
                            e.x += qv * (float)kv.h[0];
                            e.y += qv * (float)kv.h[1];
                            e.z += qv * (float)kv.h[2];
                            e.w += qv * (float)kv.h[3];
                        }
                    } else {
                        const float4e* k4 = (const float4e*)p.key + (size_t)b * QDIM * T4
                                          + (t0 >> 2) + tl;
                        #pragma unroll 8
                        for (int qq = 0; qq < 32; ++qq) {
                            float4e kv = k4[(size_t)(q0 + qq) * T4];
                            e += qry[q0 + qq] * kv;
                        }
                    }
                }
                ep[qg][tl] = e;
                __syncthreads();
                if (tid < 256 && t0 < n) {
                    float4e r = (ep[0][tid] + ep[1][tid]) + (ep[2][tid] + ep[3][tid]);
                    ((float4e*)s_sc)[(t0 >> 2) + tid] = r;
                }
                __syncthreads();
            }
        }

        // ---- max over t<n ----
        float m = -INFINITY;
        for (int t = tid; t < n; t += 1024) m = fmaxf(m, s_sc[t]);
        #pragma unroll
        for (int off = 32; off; off >>= 1) m = fmaxf(m, __shfl_xor(m, off));
        if ((tid & 63) == 0) wred[tid >> 6] = m;
        __syncthreads();
        if (tid == 0) {
            float r = wred[0];
            #pragma unroll
            for (int i = 1; i < 16; ++i) r = fmaxf(r, wred[i]);
            bcast = r;
        }
        __syncthreads();
        m = bcast;

        // ---- exp + sum ----
        float z = 0.f;
        for (int t = tid; t < T; t += 1024) {
            float pv = 0.f;
            if (t < n) { pv = expf(s_sc[t] - m); z += pv; }
            s_sc[t] = pv;
        }
        #pragma unroll
        for (int off = 32; off; off >>= 1) z += __shfl_xor(z, off);
        if ((tid & 63) == 0) wred[tid >> 6] = z;
        __syncthreads();
        if (tid == 0) {
            float r = 0.f;
            #pragma unroll
            for (int i = 0; i < 16; ++i) r += wred[i];
            bcast = r;
        }
        __syncthreads();
        const float Z = bcast;

        // ---- scores out ----
        float* so = p.outS + ((size_t)b * p.S + s) * T;
        for (int t = tid; t < T; t += 1024) {
            float sc = s_sc[t] / Z;
            s_sc[t] = sc;
            __builtin_nontemporal_store(sc, so + t);
        }
        __syncthreads();

        // ---- ctx = sum_{t<n} score[t] * val[b][t][:] ----
        {
            const int tg = tid >> 5, cq = tid & 31;
            float ax = 0, ay = 0, az = 0, aw = 0;
            if (KV16) {
                const uint2e* v2 = (const uint2e*)p.valh + (size_t)b * T * 32 + cq;
                #pragma unroll 4
                for (int t = tg; t < n; t += 32) {
                    float sv = s_sc[t];
                    H4 vv; vv.u = v2[(size_t)t * 32];
                    ax += sv * (float)vv.h[0]; ay += sv * (float)vv.h[1];
                    az += sv * (float)vv.h[2]; aw += sv * (float)vv.h[3];
                }
            } else {
                const float4e* v4 = (const float4e*)p.val + (size_t)b * T * 32 + cq;
                #pragma unroll 4
                for (int t = tg; t < n; t += 32) {
                    float   sv = s_sc[t];
                    float4e vv = v4[(size_t)t * 32];
                    ax += sv * vv.x; ay += sv * vv.y; az += sv * vv.z; aw += sv * vv.w;
                }
            }
            ax += __shfl_xor(ax, 32); ay += __shfl_xor(ay, 32);
            az += __shfl_xor(az, 32); aw += __shfl_xor(aw, 32);
            if ((tid & 63) < 32) {
                const int w = tid >> 6;
                red[w][cq * 4 + 0] = ax; red[w][cq * 4 + 1] = ay;
                red[w][cq * 4 + 2] = az; red[w][cq * 4 + 3] = aw;
            }
        }
        __syncthreads();
        if (tid < CTXD) {
            float a = 0.f;
            #pragma unroll
            for (int w = 0; w < 16; ++w) a += red[w][tid];
            ctx[tid] = a;
            xh0[256 + tid] = a;
        }
        if (tid < HID) xh0[tid] = h[2][tid];
        __syncthreads();

        // ---- MLP1: hid = relu(feat @ Ws1^T + bs1) ----
        {
            const int j = tid & 255, ch = tid >> 8;
            const uint4e* w = (const uint4e*)p.Ws1h + (size_t)(ch * 12) * 256 + j;
            H8 cc; cc.u = w[0];
            float a = 0.f;
            #pragma unroll 2
            for (int u = 0; u < 12; ++u) {
                H8 nx; nx.u = w[(size_t)(u + 1) * 256];
                const float* x = xh0 + (ch * 12 + u) * 8;
                a += (float)cc.h[0] * x[0] + (float)cc.h[1] * x[1]
                   + (float)cc.h[2] * x[2] + (float)cc.h[3] * x[3]
                   + (float)cc.h[4] * x[4] + (float)cc.h[5] * x[5]
                   + (float)cc.h[6] * x[6] + (float)cc.h[7] * x[7];
                cc = nx;
            }
            gacc[ch * 256 + j] = a;
        }
        __syncthreads();
        if (tid < HID)
            hid[tid] = fmaxf(p.bs1[tid] + ((gacc[tid] + gacc[256 + tid]) + (gacc[512 + tid] + gacc[768 + tid])), 0.f);
        __syncthreads();

        // ---- predict + argmax feedback ----
        if (tid < VDNUM * 8) {
            const int v = tid >> 3, oct = tid & 7;
            const float* w2 = p.Ws2T + (size_t)oct * 32 * VDNUM + v;
            float a = 0.f;
            #pragma unroll 8
            for (int k = 0; k < 32; ++k) a += hid[oct * 32 + k] * w2[(size_t)k * VDNUM];
            predp[v * 8 + oct] = a;
        }
        __syncthreads();
        if (tid < VDNUM) {
            float a = p.bs2[tid];
            #pragma unroll
            for (int o = 0; o < 8; ++o) a += predp[tid * 8 + o];
            __builtin_nontemporal_store(a, p.outP + ((size_t)b * p.S + s) * VDNUM + tid);
            predv[tid] = a;
        }
        __syncthreads();
        if (tid == 0) {   // first-occurrence argmax (strict >)
            int best = 0; float bv = predv[0];
            for (int v = 1; v < VDNUM; ++v) if (predv[v] > bv) { bv = predv[v]; best = v; }
            chr = best;
        }
        __syncthreads();
    }
}

extern "C" void kernel_launch(void* const* d_in, const int* in_sizes, int n_in,
                              void* d_out, int out_size, void* d_ws, size_t ws_size,
                              hipStream_t stream)
{
    P p;
    p.seqs  = (const int*)  d_in[0];
    p.key   = (const float*)d_in[1];
    p.val   = (const float*)d_in[2];
    p.embed = (const float*)d_in[4];
    p.Wih0  = (const float*)d_in[5];  p.Whh0 = (const float*)d_in[6];
    p.bih0  = (const float*)d_in[7];  p.bhh0 = (const float*)d_in[8];
    p.Wih1  = (const float*)d_in[9];  p.Whh1 = (const float*)d_in[10];
    p.bih1  = (const float*)d_in[11]; p.bhh1 = (const float*)d_in[12];
    p.Wih2  = (const float*)d_in[13]; p.Whh2 = (const float*)d_in[14];
    p.bih2  = (const float*)d_in[15]; p.bhh2 = (const float*)d_in[16];
    p.Wq    = (const float*)d_in[17]; p.bq   = (const float*)d_in[18];
    p.Ws1   = (const float*)d_in[19]; p.bs1  = (const float*)d_in[20];
    p.Ws2   = (const float*)d_in[21]; p.bs2  = (const float*)d_in[22];
    p.h0    = (const float*)d_in[23];
    p.c0    = (const float*)d_in[24];
    p.con   = (const float*)d_in[25];

    const int B = in_sizes[0];                  // 64
    p.T = in_sizes[1] / (B * QDIM);             // 2048
    p.S = in_sizes[3] / B;                      // 220

    // workspace layout (bytes; 16B-aligned)
    char* ws = (char*)d_ws;
    p.WH0  = (unsigned short*)(ws + 0);          // 1,048,576 B
    p.WH1  = (unsigned short*)(ws + 1048576);    // 1,310,720 B
    p.WH2  = (unsigned short*)(ws + 2359296);    // 1,310,720 B
    p.Ws1h = (unsigned short*)(ws + 3670016);    //   200,704 B
    p.bsum = (float*)(ws + 3870720);             //    12,288 B
    p.WqT4 = (float*)(ws + 3883008);             //   131,072 B
    p.Ws2T = (float*)(ws + 4014080);             //    33,792 B
    p.Ep   = (float*)(ws + 4047872);             //   135,168 B  -> end 4,183,040

    const size_t kvBytes = (size_t)B * QDIM * p.T * 2;       // 33,554,432 each
    p.keyh = (unsigned short*)(ws + 4183040);
    p.valh = (unsigned short*)(ws + 4183040 + kvBytes);
    p.dokv = (ws_size >= 4183040 + 2 * kvBytes) ? 1 : 0;

    p.outS = (float*)d_out;
    p.outP = p.outS + (size_t)B * p.S * p.T;

    prep<<<1024, 256, 0, stream>>>(p);
    if (p.dokv) speller<true ><<<B, 1024, 0, stream>>>(p);
    else        speller<false><<<B, 1024, 0, stream>>>(p);
}